// Round 9
// baseline (648.263 us; speedup 1.0000x reference)
//
#include <hip/hip_runtime.h>
#include <stdint.h>

constexpr int SEQ = 1024;
constexpr int BSZ = 8;
constexpr int NHEAD = 16;
constexpr int DHEAD = 64;
constexpr int DMODEL = 1024;

using u16 = unsigned short;
using bf16x8 = __attribute__((ext_vector_type(8))) short;
using f32x4 = __attribute__((ext_vector_type(4))) float;

__device__ __forceinline__ float bf2f(u16 u) {
  union { unsigned int i; float f; } c; c.i = ((unsigned int)u) << 16; return c.f;
}
// HW packed f32->bf16 (RNE): lo16 = cvt(a), hi16 = cvt(b)
__device__ __forceinline__ unsigned cvtpk(float a, float b) {
  unsigned r; asm("v_cvt_pk_bf16_f32 %0, %1, %2" : "=v"(r) : "v"(a), "v"(b)); return r;
}
// HW 2^x
__device__ __forceinline__ float exp2v(float x) {
  float r; asm("v_exp_f32 %0, %1" : "=v"(r) : "v"(x)); return r;
}
// async global->LDS, 16B per lane; LDS dest = wave-uniform base + lane*16
__device__ __forceinline__ void gload16(const void* g, void* l) {
  __builtin_amdgcn_global_load_lds((const __attribute__((address_space(1))) void*)g,
                                   (__attribute__((address_space(3))) void*)l, 16, 0, 0);
}
__device__ __forceinline__ bf16x8 cvt8(const float* src) {
  f32x4 a = *(const f32x4*)src;
  f32x4 b = *(const f32x4*)(src + 4);
  union { unsigned u[4]; bf16x8 v; } o;
  o.u[0] = cvtpk(a[0], a[1]); o.u[1] = cvtpk(a[2], a[3]);
  o.u[2] = cvtpk(b[0], b[1]); o.u[3] = cvtpk(b[2], b[3]);
  return o.v;
}
// swizzled accessors: [*][64] tiles and the [64][128] D buffer
__device__ __forceinline__ bf16x8 rd8(const u16* base, int row, int col) {
  return *(const bf16x8*)((const char*)base + (((row * 64 + col) * 2) ^ ((row & 7) << 4)));
}
__device__ __forceinline__ bf16x8 rd8_128(const u16* base, int row, int col) {
  return *(const bf16x8*)((const char*)base + (((row * 128 + col) * 2) ^ ((row & 7) << 4)));
}
__device__ __forceinline__ void wr128(u16* base, int row, int col, u16 v) {
  *(u16*)((char*)base + (((row * 128 + col) * 2) ^ ((row & 7) << 4))) = v;
}

// ---------------- bf16-MFMA GEMM: C = A(MxK) @ BT(NxK)^T, 128x128 tile, BK=64
template <int A32, int C32>
__global__ __launch_bounds__(256, 2) void gemm_bt(
    const void* __restrict__ Ap, int lda,
    const u16* __restrict__ BT, int ldb,
    void* __restrict__ Cp, int ldc, int K) {
  __shared__ __align__(16) u16 As[128 * 64];
  __shared__ __align__(16) u16 Bs[128 * 64];
  const int t = threadIdx.x;
  const int lane = t & 63;
  const int w = t >> 6, wr = w >> 1, wc = w & 1;
  const int l15 = lane & 15, l4 = lane >> 4;
  const int row0 = blockIdx.y * 128, col0 = blockIdx.x * 128;
  f32x4 acc[4][4] = {};
  for (int k0 = 0; k0 < K; k0 += 64) {
#pragma unroll
    for (int q = 0; q < 4; q++) {
      int u = q * 256 + t;
      int r = u >> 3, c8 = u & 7;
      int sc8 = c8 ^ (r & 7);
      int ub = (q * 256 + (t & ~63)) * 8;
      gload16(BT + (size_t)(col0 + r) * ldb + k0 + sc8 * 8, Bs + ub);
      if (A32) {
        const float* src = (const float*)Ap + (size_t)(row0 + r) * lda + k0 + sc8 * 8;
        *(bf16x8*)(As + (size_t)u * 8) = cvt8(src);
      } else {
        gload16((const u16*)Ap + (size_t)(row0 + r) * lda + k0 + sc8 * 8, As + ub);
      }
    }
    __syncthreads();
#pragma unroll
    for (int kk = 0; kk < 2; kk++) {
      bf16x8 av[4], bv[4];
#pragma unroll
      for (int f = 0; f < 4; f++) {
        int kb = kk * 32 + l4 * 8;
        av[f] = rd8(As, wr * 64 + f * 16 + l15, kb);
        bv[f] = rd8(Bs, wc * 64 + f * 16 + l15, kb);
      }
#pragma unroll
      for (int fr = 0; fr < 4; fr++)
#pragma unroll
        for (int fc = 0; fc < 4; fc++)
          acc[fr][fc] = __builtin_amdgcn_mfma_f32_16x16x32_bf16(av[fr], bv[fc], acc[fr][fc], 0, 0, 0);
    }
    __syncthreads();
  }
#pragma unroll
  for (int fr = 0; fr < 4; fr++)
#pragma unroll
    for (int fc = 0; fc < 4; fc++) {
      int col = col0 + wc * 64 + fc * 16 + l15;
      int rw0 = row0 + wr * 64 + fr * 16 + l4 * 4;
      if (C32) {
#pragma unroll
        for (int r = 0; r < 4; r++)
          ((float*)Cp)[(size_t)(rw0 + r) * ldc + col] = acc[fr][fc][r];
      } else {
        unsigned p01 = cvtpk(acc[fr][fc][0], acc[fr][fc][1]);
        unsigned p23 = cvtpk(acc[fr][fc][2], acc[fr][fc][3]);
        u16* cb = (u16*)Cp;
        cb[(size_t)(rw0 + 0) * ldc + col] = (u16)p01;
        cb[(size_t)(rw0 + 1) * ldc + col] = (u16)(p01 >> 16);
        cb[(size_t)(rw0 + 2) * ldc + col] = (u16)p23;
        cb[(size_t)(rw0 + 3) * ldc + col] = (u16)(p23 >> 16);
      }
    }
}

// ---------------- corr[n][m] = (rrb - rwb)[n] . R[m]  (f32, 64KB)
__global__ void corr_kernel(const u16* __restrict__ Rh, const float* __restrict__ rwb,
                            const float* __restrict__ rrb, float* __restrict__ corrR) {
  const int m0 = blockIdx.x * 64, n = blockIdx.y;
  const int t = threadIdx.x, r = t >> 2, q = t & 3;
  float p = 0.f;
#pragma unroll
  for (int e = 0; e < 16; e++) {
    int d = q * 16 + e;
    p += (rrb[n * DHEAD + d] - rwb[n * DHEAD + d]) * bf2f(Rh[(size_t)(m0 + r) * DMODEL + n * DHEAD + d]);
  }
  p += __shfl_xor(p, 1, 4);
  p += __shfl_xor(p, 2, 4);
  if (q == 0) corrR[n * SEQ + m0 + r] = p;
}

// ---------------- fused flash attention, barrier-free main loop:
// Q frags hoisted to regs; K/V/R B-frags loaded global->reg (L2-hot via XCD swizzle);
// D/P scratch in wave-private LDS strips.
__global__ __launch_bounds__(256, 4) void flash_fused(
    const u16* __restrict__ Qb, const u16* __restrict__ KVb,
    const u16* __restrict__ VT, const u16* __restrict__ Rh,
    const float* __restrict__ rwb, const float* __restrict__ corrR,
    u16* __restrict__ AV) {
  __shared__ __align__(16) char smem[24704];
  u16* Qs = (u16*)smem;                 // 65 x 64 (Q + rwb)
  u16* Df = (u16*)(smem + 8320);        // 64 x 128 rolling D halves (+P overlay)
  const int t = threadIdx.x;
  const int lane = t & 63;
  const int w = t >> 6;
  const int l15 = lane & 15, l4 = lane >> 4;
  const int bid = blockIdx.x;
  const int sw = (bid & 7) * 256 + (bid >> 3);   // XCD swizzle
  const int i0 = (sw & 15) * 64;
  const int z = sw >> 4, b = z >> 4, n = z & 15;
  const float KSC = 0.18033688f;  // 0.125 * log2(e)

  // stage Qs = Q + rwb, rows i0..i0+64 (row 64 clamped)
#pragma unroll
  for (int p = 0; p < 3; p++) {
    int u = p * 256 + t;
    if (u < 520) {
      int r = u >> 3, c8 = u & 7;
      int sc8 = c8 ^ (r & 7);
      int rq = i0 + r; if (rq > SEQ - 1) rq = SEQ - 1;
      bf16x8 qv = *(const bf16x8*)(Qb + ((size_t)rq * BSZ + b) * DMODEL + n * DHEAD + sc8 * 8);
      f32x4 b0 = *(const f32x4*)(rwb + n * DHEAD + sc8 * 8);
      f32x4 b1 = *(const f32x4*)(rwb + n * DHEAD + sc8 * 8 + 4);
      union { unsigned u4[4]; bf16x8 v; } o;
      o.u4[0] = cvtpk(bf2f((u16)qv[0]) + b0[0], bf2f((u16)qv[1]) + b0[1]);
      o.u4[1] = cvtpk(bf2f((u16)qv[2]) + b0[2], bf2f((u16)qv[3]) + b0[3]);
      o.u4[2] = cvtpk(bf2f((u16)qv[4]) + b1[0], bf2f((u16)qv[5]) + b1[1]);
      o.u4[3] = cvtpk(bf2f((u16)qv[6]) + b1[2], bf2f((u16)qv[7]) + b1[3]);
      *(bf16x8*)(Qs + (size_t)u * 8) = o.v;
    }
  }
  __syncthreads();  // the ONLY block-wide barrier
  // hoist loop-invariant Q A-fragments (rows qr0 and qr0+1)
  bf16x8 aQ[2], aD1[2];
#pragma unroll
  for (int kk = 0; kk < 2; kk++) {
    int kb = kk * 32 + l4 * 8;
    aQ[kk]  = rd8(Qs, w * 16 + l15, kb);
    aD1[kk] = rd8(Qs, w * 16 + l15 + 1, kb);
  }
  // B-frag global bases (16B-aligned loads)
  const u16* Kbase = KVb + (size_t)b * (2 * DMODEL) + n * DHEAD;      // + (j0+kr)*8*2048 + kb
  const u16* Vbase = VT + ((size_t)(b * NHEAD + n) * DHEAD) * SEQ;    // + vr*SEQ + j0 + kb
  const float* corrn = corrR + n * SEQ;

  // prologue D-tile: base = 960 - i0, qo = 0, into half 0
  const int baseP = (SEQ - 64) - i0;
  {
    float cP[4];
#pragma unroll
    for (int fc = 0; fc < 4; fc++) cP[fc] = corrn[baseP + fc * 16 + l15];
    f32x4 dp[4] = {};
#pragma unroll
    for (int kk = 0; kk < 2; kk++) {
      int kb = kk * 32 + l4 * 8;
#pragma unroll
      for (int fc = 0; fc < 4; fc++) {
        bf16x8 rB = *(const bf16x8*)(Rh + (size_t)(baseP + fc * 16 + l15) * DMODEL + n * DHEAD + kb);
        dp[fc] = __builtin_amdgcn_mfma_f32_16x16x32_bf16(aQ[kk], rB, dp[fc], 0, 0, 0);
      }
    }
#pragma unroll
    for (int r = 0; r < 4; r++) {
      int row = w * 16 + l4 * 4 + r;
      unsigned d01 = cvtpk(dp[0][r] + cP[0], dp[1][r] + cP[1]);
      unsigned d23 = cvtpk(dp[2][r] + cP[2], dp[3][r] + cP[3]);
      wr128(Df, row, 0 * 16 + l15, (u16)d01);
      wr128(Df, row, 1 * 16 + l15, (u16)(d01 >> 16));
      wr128(Df, row, 2 * 16 + l15, (u16)d23);
      wr128(Df, row, 3 * 16 + l15, (u16)(d23 >> 16));
    }
  }
  f32x4 O[4] = {};
  float M[4], Lp[4];
#pragma unroll
  for (int r = 0; r < 4; r++) { M[r] = -1e30f; Lp[r] = 0.f; }
  float spec = 0.f;

  for (int jj = 0; jj < 16; jj++) {
    const int j0 = jj * 64;
    const int dlt = j0 - i0;
    const int base2 = (dlt < 0) ? dlt + SEQ : dlt;
    const int qo2 = (dlt >= 0) ? 1 : 0;
    const int off = (jj & 1) << 6;       // half holding the OLD tile (D1)
    float cr[4];
#pragma unroll
    for (int fc = 0; fc < 4; fc++) cr[fc] = corrn[base2 + fc * 16 + l15];
    // QK^T + new D-tile (8+8 MFMA), B-frags straight from L2
    f32x4 sacc[4] = {}, dnew[4] = {};
    __builtin_amdgcn_s_setprio(1);
#pragma unroll
    for (int kk = 0; kk < 2; kk++) {
      int kb = kk * 32 + l4 * 8;
      bf16x8 aD = qo2 ? aD1[kk] : aQ[kk];
#pragma unroll
      for (int fc = 0; fc < 4; fc++) {
        int br = fc * 16 + l15;
        bf16x8 kB = *(const bf16x8*)(Kbase + (size_t)(j0 + br) * (BSZ * 2 * DMODEL) + kb);
        bf16x8 rB = *(const bf16x8*)(Rh + (size_t)(base2 + br) * DMODEL + n * DHEAD + kb);
        sacc[fc] = __builtin_amdgcn_mfma_f32_16x16x32_bf16(aQ[kk], kB, sacc[fc], 0, 0, 0);
        dnew[fc] = __builtin_amdgcn_mfma_f32_16x16x32_bf16(aD, rB, dnew[fc], 0, 0, 0);
      }
    }
    __builtin_amdgcn_s_setprio(0);
    // store new D (+corr) into the other half (own-wave strip)
    const int offn = off ^ 64;
#pragma unroll
    for (int r = 0; r < 4; r++) {
      int row = w * 16 + l4 * 4 + r;
      unsigned d01 = cvtpk(dnew[0][r] + cr[0], dnew[1][r] + cr[1]);
      unsigned d23 = cvtpk(dnew[2][r] + cr[2], dnew[3][r] + cr[3]);
      wr128(Df, row, offn + 0 * 16 + l15, (u16)d01);
      wr128(Df, row, offn + 1 * 16 + l15, (u16)(d01 >> 16));
      wr128(Df, row, offn + 2 * 16 + l15, (u16)d23);
      wr128(Df, row, offn + 3 * 16 + l15, (u16)(d23 >> 16));
    }
    // spec carry for next iter: old-half [63][63] (wave 3 strip; BEFORE P overwrites it)
    float specnext = 0.f;
    if (w == 3)
      specnext = bf2f(*(const u16*)((const char*)Df + ((63 * 256) | ((((off + 63) * 2) ^ 0x70)))));
    // gather BD (uniform dlt-specialized) + log2-softmax (defer-max 11.5) + P store
    const float fix = (dlt == 64) ? 0.f : spec;
#pragma unroll
    for (int r = 0; r < 4; r++) {
      const int lrow = w * 16 + l4 * 4 + r;
      const int rbase = lrow * 256;
      const int swz = (lrow & 7) << 4;
      float v2[4];
      if (dlt < 0) {
        const int K = off + 63 - lrow;
#pragma unroll
        for (int fc = 0; fc < 4; fc++) {
          int col = (fc * 16 + l15 + K) & 127;
          float bd = bf2f(*(const u16*)((const char*)Df + (rbase | ((col * 2) ^ swz))));
          v2[fc] = (sacc[fc][r] + bd) * KSC;
        }
      } else if (dlt == 0) {
#pragma unroll
        for (int fc = 0; fc < 4; fc++) {
          int dj = fc * 16 + l15 - lrow;
          int ul = (dj <= 0) ? dj + 63 : dj + 62;
          int col = (off + ul) & 127;
          float bd = bf2f(*(const u16*)((const char*)Df + (rbase | ((col * 2) ^ swz))));
          if (dj == 1) bd = 0.f;
          v2[fc] = (sacc[fc][r] + bd) * KSC;
        }
      } else {
        const int K = 62 - lrow;
#pragma unroll
        for (int fc = 0; fc < 4; fc++) {
          int ul = fc * 16 + l15 + K;
          int col = (off + ((ul < 0) ? 0 : ul)) & 127;
          float bd = bf2f(*(const u16*)((const char*)Df + (rbase | ((col * 2) ^ swz))));
          if (ul < 0) bd = fix;
          v2[fc] = (sacc[fc][r] + bd) * KSC;
        }
      }
      float tm = fmaxf(fmaxf(v2[0], v2[1]), fmaxf(v2[2], v2[3]));
      unsigned long long bal = __ballot(tm > M[r] + 11.5f);
      if ((bal >> (l4 * 16)) & 0xFFFFull) {
        for (int mk = 1; mk < 16; mk <<= 1) tm = fmaxf(tm, __shfl_xor(tm, mk, 16));
        float alpha = exp2v(M[r] - tm);
        Lp[r] *= alpha;
#pragma unroll
        for (int fd = 0; fd < 4; fd++) O[fd][r] *= alpha;
        M[r] = tm;
      }
      float e0 = exp2v(v2[0] - M[r]), e1 = exp2v(v2[1] - M[r]);
      float e2 = exp2v(v2[2] - M[r]), e3 = exp2v(v2[3] - M[r]);
      Lp[r] += (e0 + e1) + (e2 + e3);
      unsigned p01 = cvtpk(e0, e1), p23 = cvtpk(e2, e3);
      wr128(Df, lrow, off + 0 * 16 + l15, (u16)p01);
      wr128(Df, lrow, off + 1 * 16 + l15, (u16)(p01 >> 16));
      wr128(Df, lrow, off + 2 * 16 + l15, (u16)p23);
      wr128(Df, lrow, off + 3 * 16 + l15, (u16)(p23 >> 16));
    }
    spec = specnext;
    // PV (V B-frags straight from L2)
    __builtin_amdgcn_s_setprio(1);
#pragma unroll
    for (int kk = 0; kk < 2; kk++) {
      int kb = kk * 32 + l4 * 8;
      bf16x8 a = rd8_128(Df, w * 16 + l15, off + kb);
#pragma unroll
      for (int fd = 0; fd < 4; fd++) {
        bf16x8 vB = *(const bf16x8*)(Vbase + (size_t)(fd * 16 + l15) * SEQ + j0 + kb);
        O[fd] = __builtin_amdgcn_mfma_f32_16x16x32_bf16(a, vB, O[fd], 0, 0, 0);
      }
    }
    __builtin_amdgcn_s_setprio(0);
  }
  float Lf[4];
#pragma unroll
  for (int r = 0; r < 4; r++) {
    float Lt = Lp[r];
    for (int mk = 1; mk < 16; mk <<= 1) Lt += __shfl_xor(Lt, mk, 16);
    Lf[r] = 1.f / Lt;
  }
#pragma unroll
  for (int fd = 0; fd < 4; fd++) {
    int d = fd * 16 + l15;
    int iq0 = i0 + w * 16 + l4 * 4;
    unsigned p01 = cvtpk(O[fd][0] * Lf[0], O[fd][1] * Lf[1]);
    unsigned p23 = cvtpk(O[fd][2] * Lf[2], O[fd][3] * Lf[3]);
    AV[((size_t)(iq0 + 0) * BSZ + b) * DMODEL + n * DHEAD + d] = (u16)p01;
    AV[((size_t)(iq0 + 1) * BSZ + b) * DMODEL + n * DHEAD + d] = (u16)(p01 >> 16);
    AV[((size_t)(iq0 + 2) * BSZ + b) * DMODEL + n * DHEAD + d] = (u16)p23;
    AV[((size_t)(iq0 + 3) * BSZ + b) * DMODEL + n * DHEAD + d] = (u16)(p23 >> 16);
  }
}

// ---------------- weight transpose + f32->bf16: out(CxR, bf16) = in(RxC, f32)^T
__global__ void wtrans(const float* __restrict__ in, u16* __restrict__ out, int R, int C) {
  __shared__ unsigned int lds[64][65];
  const int t = threadIdx.x;
  const int c0 = blockIdx.x * 64, r0 = blockIdx.y * 64;
#pragma unroll
  for (int p = 0; p < 2; p++) {
    int u = p * 256 + t;
    int r = u >> 3, c8 = u & 7;
    const float* src = in + (size_t)(r0 + r) * C + c0 + c8 * 8;
    f32x4 v0 = *(const f32x4*)src;
    f32x4 v1 = *(const f32x4*)(src + 4);
    unsigned q0 = cvtpk(v0[0], v0[1]), q1 = cvtpk(v0[2], v0[3]);
    unsigned q2 = cvtpk(v1[0], v1[1]), q3 = cvtpk(v1[2], v1[3]);
    lds[r][c8 * 8 + 0] = (u16)q0; lds[r][c8 * 8 + 1] = (u16)(q0 >> 16);
    lds[r][c8 * 8 + 2] = (u16)q1; lds[r][c8 * 8 + 3] = (u16)(q1 >> 16);
    lds[r][c8 * 8 + 4] = (u16)q2; lds[r][c8 * 8 + 5] = (u16)(q2 >> 16);
    lds[r][c8 * 8 + 6] = (u16)q3; lds[r][c8 * 8 + 7] = (u16)(q3 >> 16);
  }
  __syncthreads();
#pragma unroll
  for (int p = 0; p < 2; p++) {
    int u = p * 256 + t;
    int r = u >> 3, c8 = u & 7;
    bf16x8 v;
#pragma unroll
    for (int e = 0; e < 8; e++) v[e] = (short)lds[c8 * 8 + e][r];
    *(bf16x8*)(out + (size_t)(c0 + r) * R + r0 + c8 * 8) = v;
  }
}

// ---------------- V^T builder (V = second half of KVb rows, stride 2048)
__global__ void vtrans(const u16* __restrict__ KVb, u16* __restrict__ VT) {
  __shared__ unsigned int lds[64][65];
  const int t = threadIdx.x;
  const int s0 = blockIdx.x * 64, n = blockIdx.y, b = blockIdx.z;
#pragma unroll
  for (int p = 0; p < 2; p++) {
    int u = p * 256 + t;
    int r = u >> 3, c8 = u & 7;
    const u16* src = KVb + ((size_t)(s0 + r) * BSZ + b) * (2 * DMODEL) + DMODEL + n * DHEAD + c8 * 8;
    bf16x8 v = *(const bf16x8*)src;
#pragma unroll
    for (int e = 0; e < 8; e++) lds[r][c8 * 8 + e] = (u16)v[e];
  }
  __syncthreads();
#pragma unroll
  for (int p = 0; p < 2; p++) {
    int u = p * 256 + t;
    int r = u >> 3, c8 = u & 7;
    bf16x8 v;
#pragma unroll
    for (int e = 0; e < 8; e++) v[e] = (short)lds[c8 * 8 + e][r];
    *(bf16x8*)(VT + ((size_t)(b * NHEAD + n) * DHEAD + r) * SEQ + s0 + c8 * 8) = v;
  }
}

// ---------------- residual + LayerNorm (f32, in-place on out)
__global__ void ln_kernel(const float* __restrict__ hidden,
                          const float* __restrict__ gamma, const float* __restrict__ beta,
                          float* __restrict__ out) {
  __shared__ float wsum[4];
  __shared__ float wvar[4];
  const int row = blockIdx.x;
  const int t = threadIdx.x;
  f32x4 hv = *(const f32x4*)(hidden + (size_t)row * DMODEL + t * 4);
  f32x4 ov = *(const f32x4*)(out + (size_t)row * DMODEL + t * 4);
  float xs[4], sum = 0.f;
#pragma unroll
  for (int e = 0; e < 4; e++) { xs[e] = hv[e] + ov[e]; sum += xs[e]; }
  for (int mk = 1; mk < 64; mk <<= 1) sum += __shfl_xor(sum, mk, 64);
  if ((t & 63) == 0) wsum[t >> 6] = sum;
  __syncthreads();
  float mu = (wsum[0] + wsum[1] + wsum[2] + wsum[3]) * (1.f / DMODEL);
  float var = 0.f;
#pragma unroll
  for (int e = 0; e < 4; e++) { float d = xs[e] - mu; var += d * d; }
  for (int mk = 1; mk < 64; mk <<= 1) var += __shfl_xor(var, mk, 64);
  if ((t & 63) == 0) wvar[t >> 6] = var;
  __syncthreads();
  float rstd = rsqrtf((wvar[0] + wvar[1] + wvar[2] + wvar[3]) * (1.f / DMODEL) + 1e-5f);
  f32x4 res;
#pragma unroll
  for (int e = 0; e < 4; e++) {
    int c = t * 4 + e;
    res[e] = (xs[e] - mu) * rstd * gamma[c] + beta[c];
  }
  *(f32x4*)(out + (size_t)row * DMODEL + t * 4) = res;
}

extern "C" void kernel_launch(void* const* d_in, const int* in_sizes, int n_in,
                              void* d_out, int out_size, void* d_ws, size_t ws_size,
                              hipStream_t stream) {
  const float* hidden = (const float*)d_in[0];
  const float* relpos = (const float*)d_in[1];
  const float* enc    = (const float*)d_in[2];
  const float* W_q    = (const float*)d_in[3];
  const float* W_kv   = (const float*)d_in[4];
  const float* W_r    = (const float*)d_in[5];
  const float* W_o    = (const float*)d_in[6];
  const float* rwb    = (const float*)d_in[7];
  const float* rrb    = (const float*)d_in[8];
  const float* gamma  = (const float*)d_in[9];
  const float* beta   = (const float*)d_in[10];
  float* out = (float*)d_out;

  char* ws = (char*)d_ws;
  size_t off = 0;
  auto alloc = [&](size_t bytes) { char* p = ws + off; off += (bytes + 255) & ~(size_t)255; return p; };
  const size_t MB = 1024 * 1024;
  u16* WOT  = (u16*)alloc(2 * MB);
  u16* Qb   = (u16*)alloc(16 * MB);
  u16* KVb  = (u16*)alloc(32 * MB);      // K cols 0..1023, V cols 1024..2047 per row
  u16* VT   = (u16*)alloc(16 * MB);
  u16* AV   = (u16*)alloc(16 * MB);
  u16* Rh   = (u16*)alloc(2 * MB);
  float* corrR = (float*)alloc(NHEAD * SEQ * 4);
  u16* WQT  = (u16*)alloc(2 * MB);
  u16* WKVT = (u16*)alloc(4 * MB);
  u16* WRT  = (u16*)alloc(2 * MB);
  (void)ws_size; (void)in_sizes; (void)n_in; (void)out_size;

  dim3 blk(256);
  wtrans<<<dim3(16, 16), blk, 0, stream>>>(W_q, WQT, 1024, 1024);
  wtrans<<<dim3(32, 16), blk, 0, stream>>>(W_kv, WKVT, 1024, 2048);
  wtrans<<<dim3(16, 16), blk, 0, stream>>>(W_r, WRT, 1024, 1024);
  wtrans<<<dim3(16, 16), blk, 0, stream>>>(W_o, WOT, 1024, 1024);

  gemm_bt<1, 0><<<dim3(8, 64), blk, 0, stream>>>(hidden, 1024, WQT, 1024, Qb, 1024, 1024);
  gemm_bt<1, 0><<<dim3(16, 64), blk, 0, stream>>>(enc, 1024, WKVT, 1024, KVb, 2048, 1024);
  gemm_bt<1, 0><<<dim3(8, 8), blk, 0, stream>>>(relpos, 1024, WRT, 1024, Rh, 1024, 1024);
  corr_kernel<<<dim3(16, NHEAD), blk, 0, stream>>>(Rh, rwb, rrb, corrR);
  vtrans<<<dim3(16, NHEAD, BSZ), blk, 0, stream>>>(KVb, VT);

  flash_fused<<<dim3(16 * BSZ * NHEAD), blk, 0, stream>>>(Qb, KVb, VT, Rh, rwb, corrR, AV);

  gemm_bt<0, 1><<<dim3(8, 64), blk, 0, stream>>>(AV, 1024, WOT, 1024, out, 1024, 1024);
  ln_kernel<<<dim3(8192), blk, 0, stream>>>(hidden, gamma, beta, out);
}

// Round 10
// 358.116 us; speedup vs baseline: 1.8102x; 1.8102x over previous
//
#include <hip/hip_runtime.h>
#include <stdint.h>

constexpr int SEQ = 1024;
constexpr int BSZ = 8;
constexpr int NHEAD = 16;
constexpr int DHEAD = 64;
constexpr int DMODEL = 1024;

using u16 = unsigned short;
using bf16x8 = __attribute__((ext_vector_type(8))) short;
using f32x4 = __attribute__((ext_vector_type(4))) float;

__device__ __forceinline__ float bf2f(u16 u) {
  union { unsigned int i; float f; } c; c.i = ((unsigned int)u) << 16; return c.f;
}
// HW packed f32->bf16 (RNE): lo16 = cvt(a), hi16 = cvt(b)
__device__ __forceinline__ unsigned cvtpk(float a, float b) {
  unsigned r; asm("v_cvt_pk_bf16_f32 %0, %1, %2" : "=v"(r) : "v"(a), "v"(b)); return r;
}
// HW 2^x
__device__ __forceinline__ float exp2v(float x) {
  float r; asm("v_exp_f32 %0, %1" : "=v"(r) : "v"(x)); return r;
}
// async global->LDS, 16B per lane; LDS dest = wave-uniform base + lane*16
__device__ __forceinline__ void gload16(const void* g, void* l) {
  __builtin_amdgcn_global_load_lds((const __attribute__((address_space(1))) void*)g,
                                   (__attribute__((address_space(3))) void*)l, 16, 0, 0);
}
__device__ __forceinline__ bf16x8 cvt8(const float* src) {
  f32x4 a = *(const f32x4*)src;
  f32x4 b = *(const f32x4*)(src + 4);
  union { unsigned u[4]; bf16x8 v; } o;
  o.u[0] = cvtpk(a[0], a[1]); o.u[1] = cvtpk(a[2], a[3]);
  o.u[2] = cvtpk(b[0], b[1]); o.u[3] = cvtpk(b[2], b[3]);
  return o.v;
}
// swizzled accessors: [*][64] tiles and the [64][128] D buffer
__device__ __forceinline__ bf16x8 rd8(const u16* base, int row, int col) {
  return *(const bf16x8*)((const char*)base + (((row * 64 + col) * 2) ^ ((row & 7) << 4)));
}
__device__ __forceinline__ bf16x8 rd8_128(const u16* base, int row, int col) {
  return *(const bf16x8*)((const char*)base + (((row * 128 + col) * 2) ^ ((row & 7) << 4)));
}
__device__ __forceinline__ void wr128(u16* base, int row, int col, u16 v) {
  *(u16*)((char*)base + (((row * 128 + col) * 2) ^ ((row & 7) << 4))) = v;
}

// ---------------- bf16-MFMA GEMM: C = A(MxK) @ BT(NxK)^T, 128x128 tile, BK=64
template <int A32, int C32>
__global__ __launch_bounds__(256, 2) void gemm_bt(
    const void* __restrict__ Ap, int lda,
    const u16* __restrict__ BT, int ldb,
    void* __restrict__ Cp, int ldc, int K) {
  __shared__ __align__(16) u16 As[128 * 64];
  __shared__ __align__(16) u16 Bs[128 * 64];
  const int t = threadIdx.x;
  const int lane = t & 63;
  const int w = t >> 6, wr = w >> 1, wc = w & 1;
  const int l15 = lane & 15, l4 = lane >> 4;
  const int row0 = blockIdx.y * 128, col0 = blockIdx.x * 128;
  f32x4 acc[4][4] = {};
  for (int k0 = 0; k0 < K; k0 += 64) {
#pragma unroll
    for (int q = 0; q < 4; q++) {
      int u = q * 256 + t;
      int r = u >> 3, c8 = u & 7;
      int sc8 = c8 ^ (r & 7);
      int ub = (q * 256 + (t & ~63)) * 8;
      gload16(BT + (size_t)(col0 + r) * ldb + k0 + sc8 * 8, Bs + ub);
      if (A32) {
        const float* src = (const float*)Ap + (size_t)(row0 + r) * lda + k0 + sc8 * 8;
        *(bf16x8*)(As + (size_t)u * 8) = cvt8(src);
      } else {
        gload16((const u16*)Ap + (size_t)(row0 + r) * lda + k0 + sc8 * 8, As + ub);
      }
    }
    __syncthreads();
#pragma unroll
    for (int kk = 0; kk < 2; kk++) {
      bf16x8 av[4], bv[4];
#pragma unroll
      for (int f = 0; f < 4; f++) {
        int kb = kk * 32 + l4 * 8;
        av[f] = rd8(As, wr * 64 + f * 16 + l15, kb);
        bv[f] = rd8(Bs, wc * 64 + f * 16 + l15, kb);
      }
#pragma unroll
      for (int fr = 0; fr < 4; fr++)
#pragma unroll
        for (int fc = 0; fc < 4; fc++)
          acc[fr][fc] = __builtin_amdgcn_mfma_f32_16x16x32_bf16(av[fr], bv[fc], acc[fr][fc], 0, 0, 0);
    }
    __syncthreads();
  }
#pragma unroll
  for (int fr = 0; fr < 4; fr++)
#pragma unroll
    for (int fc = 0; fc < 4; fc++) {
      int col = col0 + wc * 64 + fc * 16 + l15;
      int rw0 = row0 + wr * 64 + fr * 16 + l4 * 4;
      if (C32) {
#pragma unroll
        for (int r = 0; r < 4; r++)
          ((float*)Cp)[(size_t)(rw0 + r) * ldc + col] = acc[fr][fc][r];
      } else {
        unsigned p01 = cvtpk(acc[fr][fc][0], acc[fr][fc][1]);
        unsigned p23 = cvtpk(acc[fr][fc][2], acc[fr][fc][3]);
        u16* cb = (u16*)Cp;
        cb[(size_t)(rw0 + 0) * ldc + col] = (u16)p01;
        cb[(size_t)(rw0 + 1) * ldc + col] = (u16)(p01 >> 16);
        cb[(size_t)(rw0 + 2) * ldc + col] = (u16)p23;
        cb[(size_t)(rw0 + 3) * ldc + col] = (u16)(p23 >> 16);
      }
    }
}

// ---------------- corr[n][m] = (rrb - rwb)[n] . R[m]  (f32, 64KB)
__global__ void corr_kernel(const u16* __restrict__ Rh, const float* __restrict__ rwb,
                            const float* __restrict__ rrb, float* __restrict__ corrR) {
  const int m0 = blockIdx.x * 64, n = blockIdx.y;
  const int t = threadIdx.x, r = t >> 2, q = t & 3;
  float p = 0.f;
#pragma unroll
  for (int e = 0; e < 16; e++) {
    int d = q * 16 + e;
    p += (rrb[n * DHEAD + d] - rwb[n * DHEAD + d]) * bf2f(Rh[(size_t)(m0 + r) * DMODEL + n * DHEAD + d]);
  }
  p += __shfl_xor(p, 1, 4);
  p += __shfl_xor(p, 2, 4);
  if (q == 0) corrR[n * SEQ + m0 + r] = p;
}

// ---------------- fused flash attention + rolling on-the-fly BD (log2-domain softmax)
// Q A-frags hoisted to registers from global (loop-invariant); K/V/R staged via
// global_load_lds (coalesced); D/P scratch in wave-private LDS strips. LDS = 40 KB.
__global__ __launch_bounds__(256, 3) void flash_fused(
    const u16* __restrict__ Qb, const u16* __restrict__ KVb,
    const u16* __restrict__ VT, const u16* __restrict__ Rh,
    const float* __restrict__ rwb, const float* __restrict__ corrR,
    u16* __restrict__ AV) {
  __shared__ __align__(16) char smem[40960];
  u16* Ks = (u16*)smem;
  u16* Vs = (u16*)(smem + 8192);
  u16* Rs = (u16*)(smem + 16384);
  u16* Df = (u16*)(smem + 24576);       // 64 x 128 rolling D halves (+P overlay)
  const int t = threadIdx.x;
  const int lane = t & 63;
  const int w = t >> 6;
  const int l15 = lane & 15, l4 = lane >> 4;
  const int bid = blockIdx.x;
  const int sw = (bid & 7) * 256 + (bid >> 3);   // XCD swizzle
  const int i0 = (sw & 15) * 64;
  const int z = sw >> 4, b = z >> 4, n = z & 15;
  const float KSC = 0.18033688f;  // 0.125 * log2(e)

  // hoist loop-invariant Q A-fragments straight from global (+rwb, cvt_pk)
  bf16x8 aQ[2], aD1[2];
  {
    const int row0 = i0 + w * 16 + l15;
    int row1 = row0 + 1; if (row1 > SEQ - 1) row1 = SEQ - 1;
#pragma unroll
    for (int kk = 0; kk < 2; kk++) {
      int kb = kk * 32 + l4 * 8;
      f32x4 b0 = *(const f32x4*)(rwb + n * DHEAD + kb);
      f32x4 b1 = *(const f32x4*)(rwb + n * DHEAD + kb + 4);
      bf16x8 q0 = *(const bf16x8*)(Qb + ((size_t)row0 * BSZ + b) * DMODEL + n * DHEAD + kb);
      bf16x8 q1 = *(const bf16x8*)(Qb + ((size_t)row1 * BSZ + b) * DMODEL + n * DHEAD + kb);
      union { unsigned u4[4]; bf16x8 v; } o0, o1;
      o0.u4[0] = cvtpk(bf2f((u16)q0[0]) + b0[0], bf2f((u16)q0[1]) + b0[1]);
      o0.u4[1] = cvtpk(bf2f((u16)q0[2]) + b0[2], bf2f((u16)q0[3]) + b0[3]);
      o0.u4[2] = cvtpk(bf2f((u16)q0[4]) + b1[0], bf2f((u16)q0[5]) + b1[1]);
      o0.u4[3] = cvtpk(bf2f((u16)q0[6]) + b1[2], bf2f((u16)q0[7]) + b1[3]);
      o1.u4[0] = cvtpk(bf2f((u16)q1[0]) + b0[0], bf2f((u16)q1[1]) + b0[1]);
      o1.u4[1] = cvtpk(bf2f((u16)q1[2]) + b0[2], bf2f((u16)q1[3]) + b0[3]);
      o1.u4[2] = cvtpk(bf2f((u16)q1[4]) + b1[0], bf2f((u16)q1[5]) + b1[1]);
      o1.u4[3] = cvtpk(bf2f((u16)q1[6]) + b1[2], bf2f((u16)q1[7]) + b1[3]);
      aQ[kk] = o0.v;
      aD1[kk] = o1.v;
    }
  }
  const float* corrn = corrR + n * SEQ;
  // prologue D-tile: base = 960 - i0, qo = 0, into half 0
  const int baseP = (SEQ - 64) - i0;
#pragma unroll
  for (int q = 0; q < 2; q++) {
    int u = q * 256 + t;
    int r = u >> 3, c8 = u & 7;
    int sc8 = c8 ^ (r & 7);
    int ub = (q * 256 + (t & ~63)) * 8;
    gload16(Rh + (size_t)(baseP + r) * DMODEL + n * DHEAD + sc8 * 8, Rs + ub);
  }
  float cP[4];
#pragma unroll
  for (int fc = 0; fc < 4; fc++) cP[fc] = corrn[baseP + fc * 16 + l15];
  __syncthreads();
  {
    f32x4 dp[4] = {};
#pragma unroll
    for (int kk = 0; kk < 2; kk++) {
      int kb = kk * 32 + l4 * 8;
#pragma unroll
      for (int fc = 0; fc < 4; fc++)
        dp[fc] = __builtin_amdgcn_mfma_f32_16x16x32_bf16(aQ[kk], rd8(Rs, fc * 16 + l15, kb), dp[fc], 0, 0, 0);
    }
#pragma unroll
    for (int r = 0; r < 4; r++) {
      int row = w * 16 + l4 * 4 + r;
      unsigned d01 = cvtpk(dp[0][r] + cP[0], dp[1][r] + cP[1]);
      unsigned d23 = cvtpk(dp[2][r] + cP[2], dp[3][r] + cP[3]);
      wr128(Df, row, 0 * 16 + l15, (u16)d01);
      wr128(Df, row, 1 * 16 + l15, (u16)(d01 >> 16));
      wr128(Df, row, 2 * 16 + l15, (u16)d23);
      wr128(Df, row, 3 * 16 + l15, (u16)(d23 >> 16));
    }
  }
  f32x4 O[4] = {};
  float M[4], Lp[4];
#pragma unroll
  for (int r = 0; r < 4; r++) { M[r] = -1e30f; Lp[r] = 0.f; }
  float spec = 0.f;

  for (int jj = 0; jj < 16; jj++) {
    const int j0 = jj * 64;
    const int dlt = j0 - i0;
    const int base2 = (dlt < 0) ? dlt + SEQ : dlt;
    const int qo2 = (dlt >= 0) ? 1 : 0;
    const int off = (jj & 1) << 6;       // half holding the OLD tile (D1)
    __syncthreads();                      // all waves done reading Ks/Vs/Rs
#pragma unroll
    for (int q = 0; q < 2; q++) {
      int u = q * 256 + t;
      int r = u >> 3, c8 = u & 7;
      int sc8 = c8 ^ (r & 7);
      int ub = (q * 256 + (t & ~63)) * 8;
      gload16(KVb + ((size_t)(j0 + r) * BSZ + b) * (2 * DMODEL) + n * DHEAD + sc8 * 8, Ks + ub);
      gload16(VT + ((size_t)(b * NHEAD + n) * DHEAD + r) * SEQ + j0 + sc8 * 8, Vs + ub);
      gload16(Rh + (size_t)(base2 + r) * DMODEL + n * DHEAD + sc8 * 8, Rs + ub);
    }
    float cr[4];
#pragma unroll
    for (int fc = 0; fc < 4; fc++) cr[fc] = corrn[base2 + fc * 16 + l15];
    __syncthreads();
    // QK^T + new D-tile (8+8 MFMA)
    f32x4 sacc[4] = {}, dnew[4] = {};
    __builtin_amdgcn_s_setprio(1);
#pragma unroll
    for (int kk = 0; kk < 2; kk++) {
      int kb = kk * 32 + l4 * 8;
      bf16x8 aD = qo2 ? aD1[kk] : aQ[kk];
#pragma unroll
      for (int fc = 0; fc < 4; fc++) {
        int br = fc * 16 + l15;
        sacc[fc] = __builtin_amdgcn_mfma_f32_16x16x32_bf16(aQ[kk], rd8(Ks, br, kb), sacc[fc], 0, 0, 0);
        dnew[fc] = __builtin_amdgcn_mfma_f32_16x16x32_bf16(aD, rd8(Rs, br, kb), dnew[fc], 0, 0, 0);
      }
    }
    __builtin_amdgcn_s_setprio(0);
    // store new D (+corr) into the other half (own-wave strip)
    const int offn = off ^ 64;
#pragma unroll
    for (int r = 0; r < 4; r++) {
      int row = w * 16 + l4 * 4 + r;
      unsigned d01 = cvtpk(dnew[0][r] + cr[0], dnew[1][r] + cr[1]);
      unsigned d23 = cvtpk(dnew[2][r] + cr[2], dnew[3][r] + cr[3]);
      wr128(Df, row, offn + 0 * 16 + l15, (u16)d01);
      wr128(Df, row, offn + 1 * 16 + l15, (u16)(d01 >> 16));
      wr128(Df, row, offn + 2 * 16 + l15, (u16)d23);
      wr128(Df, row, offn + 3 * 16 + l15, (u16)(d23 >> 16));
    }
    // spec carry for next iter: old-half [63][63] (wave 3 strip; BEFORE P overwrites it)
    float specnext = 0.f;
    if (w == 3)
      specnext = bf2f(*(const u16*)((const char*)Df + ((63 * 256) | ((((off + 63) * 2) ^ 0x70)))));
    // gather BD (uniform dlt-specialized) + log2-softmax (defer-max 11.5) + P store
    const float fix = (dlt == 64) ? 0.f : spec;
#pragma unroll
    for (int r = 0; r < 4; r++) {
      const int lrow = w * 16 + l4 * 4 + r;
      const int rbase = lrow * 256;
      const int swz = (lrow & 7) << 4;
      float v2[4];
      if (dlt < 0) {
        const int K = off + 63 - lrow;
#pragma unroll
        for (int fc = 0; fc < 4; fc++) {
          int col = (fc * 16 + l15 + K) & 127;
          float bd = bf2f(*(const u16*)((const char*)Df + (rbase | ((col * 2) ^ swz))));
          v2[fc] = (sacc[fc][r] + bd) * KSC;
        }
      } else if (dlt == 0) {
#pragma unroll
        for (int fc = 0; fc < 4; fc++) {
          int dj = fc * 16 + l15 - lrow;
          int ul = (dj <= 0) ? dj + 63 : dj + 62;
          int col = (off + ul) & 127;
          float bd = bf2f(*(const u16*)((const char*)Df + (rbase | ((col * 2) ^ swz))));
          if (dj == 1) bd = 0.f;
          v2[fc] = (sacc[fc][r] + bd) * KSC;
        }
      } else {
        const int K = 62 - lrow;
#pragma unroll
        for (int fc = 0; fc < 4; fc++) {
          int ul = fc * 16 + l15 + K;
          int col = (off + ((ul < 0) ? 0 : ul)) & 127;
          float bd = bf2f(*(const u16*)((const char*)Df + (rbase | ((col * 2) ^ swz))));
          if (ul < 0) bd = fix;
          v2[fc] = (sacc[fc][r] + bd) * KSC;
        }
      }
      float tm = fmaxf(fmaxf(v2[0], v2[1]), fmaxf(v2[2], v2[3]));
      unsigned long long bal = __ballot(tm > M[r] + 11.5f);
      if ((bal >> (l4 * 16)) & 0xFFFFull) {
        for (int mk = 1; mk < 16; mk <<= 1) tm = fmaxf(tm, __shfl_xor(tm, mk, 16));
        float alpha = exp2v(M[r] - tm);
        Lp[r] *= alpha;
#pragma unroll
        for (int fd = 0; fd < 4; fd++) O[fd][r] *= alpha;
        M[r] = tm;
      }
      float e0 = exp2v(v2[0] - M[r]), e1 = exp2v(v2[1] - M[r]);
      float e2 = exp2v(v2[2] - M[r]), e3 = exp2v(v2[3] - M[r]);
      Lp[r] += (e0 + e1) + (e2 + e3);
      unsigned p01 = cvtpk(e0, e1), p23 = cvtpk(e2, e3);
      wr128(Df, lrow, off + 0 * 16 + l15, (u16)p01);
      wr128(Df, lrow, off + 1 * 16 + l15, (u16)(p01 >> 16));
      wr128(Df, lrow, off + 2 * 16 + l15, (u16)p23);
      wr128(Df, lrow, off + 3 * 16 + l15, (u16)(p23 >> 16));
    }
    spec = specnext;
    // PV
    __builtin_amdgcn_s_setprio(1);
#pragma unroll
    for (int kk = 0; kk < 2; kk++) {
      int kb = kk * 32 + l4 * 8;
      bf16x8 a = rd8_128(Df, w * 16 + l15, off + kb);
#pragma unroll
      for (int fd = 0; fd < 4; fd++)
        O[fd] = __builtin_amdgcn_mfma_f32_16x16x32_bf16(a, rd8(Vs, fd * 16 + l15, kb), O[fd], 0, 0, 0);
    }
    __builtin_amdgcn_s_setprio(0);
  }
  float Lf[4];
#pragma unroll
  for (int r = 0; r < 4; r++) {
    float Lt = Lp[r];
    for (int mk = 1; mk < 16; mk <<= 1) Lt += __shfl_xor(Lt, mk, 16);
    Lf[r] = 1.f / Lt;
  }
#pragma unroll
  for (int fd = 0; fd < 4; fd++) {
    int d = fd * 16 + l15;
    int iq0 = i0 + w * 16 + l4 * 4;
    unsigned p01 = cvtpk(O[fd][0] * Lf[0], O[fd][1] * Lf[1]);
    unsigned p23 = cvtpk(O[fd][2] * Lf[2], O[fd][3] * Lf[3]);
    AV[((size_t)(iq0 + 0) * BSZ + b) * DMODEL + n * DHEAD + d] = (u16)p01;
    AV[((size_t)(iq0 + 1) * BSZ + b) * DMODEL + n * DHEAD + d] = (u16)(p01 >> 16);
    AV[((size_t)(iq0 + 2) * BSZ + b) * DMODEL + n * DHEAD + d] = (u16)p23;
    AV[((size_t)(iq0 + 3) * BSZ + b) * DMODEL + n * DHEAD + d] = (u16)(p23 >> 16);
  }
}

// ---------------- weight transpose + f32->bf16: out(CxR, bf16) = in(RxC, f32)^T
__global__ void wtrans(const float* __restrict__ in, u16* __restrict__ out, int R, int C) {
  __shared__ unsigned int lds[64][65];
  const int t = threadIdx.x;
  const int c0 = blockIdx.x * 64, r0 = blockIdx.y * 64;
#pragma unroll
  for (int p = 0; p < 2; p++) {
    int u = p * 256 + t;
    int r = u >> 3, c8 = u & 7;
    const float* src = in + (size_t)(r0 + r) * C + c0 + c8 * 8;
    f32x4 v0 = *(const f32x4*)src;
    f32x4 v1 = *(const f32x4*)(src + 4);
    unsigned q0 = cvtpk(v0[0], v0[1]), q1 = cvtpk(v0[2], v0[3]);
    unsigned q2 = cvtpk(v1[0], v1[1]), q3 = cvtpk(v1[2], v1[3]);
    lds[r][c8 * 8 + 0] = (u16)q0; lds[r][c8 * 8 + 1] = (u16)(q0 >> 16);
    lds[r][c8 * 8 + 2] = (u16)q1; lds[r][c8 * 8 + 3] = (u16)(q1 >> 16);
    lds[r][c8 * 8 + 4] = (u16)q2; lds[r][c8 * 8 + 5] = (u16)(q2 >> 16);
    lds[r][c8 * 8 + 6] = (u16)q3; lds[r][c8 * 8 + 7] = (u16)(q3 >> 16);
  }
  __syncthreads();
#pragma unroll
  for (int p = 0; p < 2; p++) {
    int u = p * 256 + t;
    int r = u >> 3, c8 = u & 7;
    bf16x8 v;
#pragma unroll
    for (int e = 0; e < 8; e++) v[e] = (short)lds[c8 * 8 + e][r];
    *(bf16x8*)(out + (size_t)(c0 + r) * R + r0 + c8 * 8) = v;
  }
}

// ---------------- V^T builder (V = second half of KVb rows, stride 2048)
__global__ void vtrans(const u16* __restrict__ KVb, u16* __restrict__ VT) {
  __shared__ unsigned int lds[64][65];
  const int t = threadIdx.x;
  const int s0 = blockIdx.x * 64, n = blockIdx.y, b = blockIdx.z;
#pragma unroll
  for (int p = 0; p < 2; p++) {
    int u = p * 256 + t;
    int r = u >> 3, c8 = u & 7;
    const u16* src = KVb + ((size_t)(s0 + r) * BSZ + b) * (2 * DMODEL) + DMODEL + n * DHEAD + c8 * 8;
    bf16x8 v = *(const bf16x8*)src;
#pragma unroll
    for (int e = 0; e < 8; e++) lds[r][c8 * 8 + e] = (u16)v[e];
  }
  __syncthreads();
#pragma unroll
  for (int p = 0; p < 2; p++) {
    int u = p * 256 + t;
    int r = u >> 3, c8 = u & 7;
    bf16x8 v;
#pragma unroll
    for (int e = 0; e < 8; e++) v[e] = (short)lds[c8 * 8 + e][r];
    *(bf16x8*)(VT + ((size_t)(b * NHEAD + n) * DHEAD + r) * SEQ + s0 + c8 * 8) = v;
  }
}

// ---------------- residual + LayerNorm (f32, in-place on out)
__global__ void ln_kernel(const float* __restrict__ hidden,
                          const float* __restrict__ gamma, const float* __restrict__ beta,
                          float* __restrict__ out) {
  __shared__ float wsum[4];
  __shared__ float wvar[4];
  const int row = blockIdx.x;
  const int t = threadIdx.x;
  f32x4 hv = *(const f32x4*)(hidden + (size_t)row * DMODEL + t * 4);
  f32x4 ov = *(const f32x4*)(out + (size_t)row * DMODEL + t * 4);
  float xs[4], sum = 0.f;
#pragma unroll
  for (int e = 0; e < 4; e++) { xs[e] = hv[e] + ov[e]; sum += xs[e]; }
  for (int mk = 1; mk < 64; mk <<= 1) sum += __shfl_xor(sum, mk, 64);
  if ((t & 63) == 0) wsum[t >> 6] = sum;
  __syncthreads();
  float mu = (wsum[0] + wsum[1] + wsum[2] + wsum[3]) * (1.f / DMODEL);
  float var = 0.f;
#pragma unroll
  for (int e = 0; e < 4; e++) { float d = xs[e] - mu; var += d * d; }
  for (int mk = 1; mk < 64; mk <<= 1) var += __shfl_xor(var, mk, 64);
  if ((t & 63) == 0) wvar[t >> 6] = var;
  __syncthreads();
  float rstd = rsqrtf((wvar[0] + wvar[1] + wvar[2] + wvar[3]) * (1.f / DMODEL) + 1e-5f);
  f32x4 res;
#pragma unroll
  for (int e = 0; e < 4; e++) {
    int c = t * 4 + e;
    res[e] = (xs[e] - mu) * rstd * gamma[c] + beta[c];
  }
  *(f32x4*)(out + (size_t)row * DMODEL + t * 4) = res;
}

extern "C" void kernel_launch(void* const* d_in, const int* in_sizes, int n_in,
                              void* d_out, int out_size, void* d_ws, size_t ws_size,
                              hipStream_t stream) {
  const float* hidden = (const float*)d_in[0];
  const float* relpos = (const float*)d_in[1];
  const float* enc    = (const float*)d_in[2];
  const float* W_q    = (const float*)d_in[3];
  const float* W_kv   = (const float*)d_in[4];
  const float* W_r    = (const float*)d_in[5];
  const float* W_o    = (const float*)d_in[6];
  const float* rwb    = (const float*)d_in[7];
  const float* rrb    = (const float*)d_in[8];
  const float* gamma  = (const float*)d_in[9];
  const float* beta   = (const float*)d_in[10];
  float* out = (float*)d_out;

  char* ws = (char*)d_ws;
  size_t off = 0;
  auto alloc = [&](size_t bytes) { char* p = ws + off; off += (bytes + 255) & ~(size_t)255; return p; };
  const size_t MB = 1024 * 1024;
  u16* WOT  = (u16*)alloc(2 * MB);
  u16* Qb   = (u16*)alloc(16 * MB);
  u16* KVb  = (u16*)alloc(32 * MB);      // K cols 0..1023, V cols 1024..2047 per row
  u16* VT   = (u16*)alloc(16 * MB);
  u16* AV   = (u16*)alloc(16 * MB);
  u16* Rh   = (u16*)alloc(2 * MB);
  float* corrR = (float*)alloc(NHEAD * SEQ * 4);
  u16* WQT  = (u16*)alloc(2 * MB);
  u16* WKVT = (u16*)alloc(4 * MB);
  u16* WRT  = (u16*)alloc(2 * MB);
  (void)ws_size; (void)in_sizes; (void)n_in; (void)out_size;

  dim3 blk(256);
  wtrans<<<dim3(16, 16), blk, 0, stream>>>(W_q, WQT, 1024, 1024);
  wtrans<<<dim3(32, 16), blk, 0, stream>>>(W_kv, WKVT, 1024, 2048);
  wtrans<<<dim3(16, 16), blk, 0, stream>>>(W_r, WRT, 1024, 1024);
  wtrans<<<dim3(16, 16), blk, 0, stream>>>(W_o, WOT, 1024, 1024);

  gemm_bt<1, 0><<<dim3(8, 64), blk, 0, stream>>>(hidden, 1024, WQT, 1024, Qb, 1024, 1024);
  gemm_bt<1, 0><<<dim3(16, 64), blk, 0, stream>>>(enc, 1024, WKVT, 1024, KVb, 2048, 1024);
  gemm_bt<1, 0><<<dim3(8, 8), blk, 0, stream>>>(relpos, 1024, WRT, 1024, Rh, 1024, 1024);
  corr_kernel<<<dim3(16, NHEAD), blk, 0, stream>>>(Rh, rwb, rrb, corrR);
  vtrans<<<dim3(16, NHEAD, BSZ), blk, 0, stream>>>(KVb, VT);

  flash_fused<<<dim3(16 * BSZ * NHEAD), blk, 0, stream>>>(Qb, KVb, VT, Rh, rwb, corrR, AV);

  gemm_bt<0, 1><<<dim3(8, 64), blk, 0, stream>>>(AV, 1024, WOT, 1024, out, 1024, 1024);
  ln_kernel<<<dim3(8192), blk, 0, stream>>>(hidden, gamma, beta, out);
}

// Round 11
// 297.806 us; speedup vs baseline: 2.1768x; 1.2025x over previous
//
#include <hip/hip_runtime.h>
#include <stdint.h>

constexpr int SEQ = 1024;
constexpr int BSZ = 8;
constexpr int NHEAD = 16;
constexpr int DHEAD = 64;
constexpr int DMODEL = 1024;

using u16 = unsigned short;
using bf16x8 = __attribute__((ext_vector_type(8))) short;
using f32x4 = __attribute__((ext_vector_type(4))) float;

__device__ __forceinline__ float bf2f(u16 u) {
  union { unsigned int i; float f; } c; c.i = ((unsigned int)u) << 16; return c.f;
}
// HW packed f32->bf16 (RNE): lo16 = cvt(a), hi16 = cvt(b)
__device__ __forceinline__ unsigned cvtpk(float a, float b) {
  unsigned r; asm("v_cvt_pk_bf16_f32 %0, %1, %2" : "=v"(r) : "v"(a), "v"(b)); return r;
}
// HW 2^x
__device__ __forceinline__ float exp2v(float x) {
  float r; asm("v_exp_f32 %0, %1" : "=v"(r) : "v"(x)); return r;
}
// async global->LDS, 16B per lane; LDS dest = wave-uniform base + lane*16
__device__ __forceinline__ void gload16(const void* g, void* l) {
  __builtin_amdgcn_global_load_lds((const __attribute__((address_space(1))) void*)g,
                                   (__attribute__((address_space(3))) void*)l, 16, 0, 0);
}
__device__ __forceinline__ bf16x8 cvt8(const float* src) {
  f32x4 a = *(const f32x4*)src;
  f32x4 b = *(const f32x4*)(src + 4);
  union { unsigned u[4]; bf16x8 v; } o;
  o.u[0] = cvtpk(a[0], a[1]); o.u[1] = cvtpk(a[2], a[3]);
  o.u[2] = cvtpk(b[0], b[1]); o.u[3] = cvtpk(b[2], b[3]);
  return o.v;
}
// swizzled accessors: [*][64] tiles and the [64][128] D buffer
__device__ __forceinline__ bf16x8 rd8(const u16* base, int row, int col) {
  return *(const bf16x8*)((const char*)base + (((row * 64 + col) * 2) ^ ((row & 7) << 4)));
}
__device__ __forceinline__ bf16x8 rd8_128(const u16* base, int row, int col) {
  return *(const bf16x8*)((const char*)base + (((row * 128 + col) * 2) ^ ((row & 7) << 4)));
}
__device__ __forceinline__ void wr128(u16* base, int row, int col, u16 v) {
  *(u16*)((char*)base + (((row * 128 + col) * 2) ^ ((row & 7) << 4))) = v;
}

// ---------------- shared GEMM body: C(bf16) = A(f32, MxK) @ BT(bf16, NxK)^T, 128x128, BK=64
__device__ __forceinline__ void gemm_body_a32(
    const float* __restrict__ A, const u16* __restrict__ BT, u16* __restrict__ C,
    int ldc, int bx, int by, u16* As, u16* Bs) {
  const int t = threadIdx.x;
  const int lane = t & 63;
  const int w = t >> 6, wr = w >> 1, wc = w & 1;
  const int l15 = lane & 15, l4 = lane >> 4;
  const int row0 = by * 128, col0 = bx * 128;
  f32x4 acc[4][4] = {};
  for (int k0 = 0; k0 < 1024; k0 += 64) {
#pragma unroll
    for (int q = 0; q < 4; q++) {
      int u = q * 256 + t;
      int r = u >> 3, c8 = u & 7;
      int sc8 = c8 ^ (r & 7);
      int ub = (q * 256 + (t & ~63)) * 8;
      gload16(BT + (size_t)(col0 + r) * 1024 + k0 + sc8 * 8, Bs + ub);
      const float* src = A + (size_t)(row0 + r) * 1024 + k0 + sc8 * 8;
      *(bf16x8*)(As + (size_t)u * 8) = cvt8(src);
    }
    __syncthreads();
#pragma unroll
    for (int kk = 0; kk < 2; kk++) {
      bf16x8 av[4], bv[4];
#pragma unroll
      for (int f = 0; f < 4; f++) {
        int kb = kk * 32 + l4 * 8;
        av[f] = rd8(As, wr * 64 + f * 16 + l15, kb);
        bv[f] = rd8(Bs, wc * 64 + f * 16 + l15, kb);
      }
#pragma unroll
      for (int fr = 0; fr < 4; fr++)
#pragma unroll
        for (int fc = 0; fc < 4; fc++)
          acc[fr][fc] = __builtin_amdgcn_mfma_f32_16x16x32_bf16(av[fr], bv[fc], acc[fr][fc], 0, 0, 0);
    }
    __syncthreads();
  }
#pragma unroll
  for (int fr = 0; fr < 4; fr++)
#pragma unroll
    for (int fc = 0; fc < 4; fc++) {
      int col = col0 + wc * 64 + fc * 16 + l15;
      int rw0 = row0 + wr * 64 + fr * 16 + l4 * 4;
      unsigned p01 = cvtpk(acc[fr][fc][0], acc[fr][fc][1]);
      unsigned p23 = cvtpk(acc[fr][fc][2], acc[fr][fc][3]);
      C[(size_t)(rw0 + 0) * ldc + col] = (u16)p01;
      C[(size_t)(rw0 + 1) * ldc + col] = (u16)(p01 >> 16);
      C[(size_t)(rw0 + 2) * ldc + col] = (u16)p23;
      C[(size_t)(rw0 + 3) * ldc + col] = (u16)(p23 >> 16);
    }
}

// ---------------- fused Q/KV/R projection launch (flat 1600-block grid)
__global__ __launch_bounds__(256, 2) void gemm3(
    const float* __restrict__ hidden, const float* __restrict__ enc,
    const float* __restrict__ relpos,
    const u16* __restrict__ WQT, const u16* __restrict__ WKVT, const u16* __restrict__ WRT,
    u16* __restrict__ Qb, u16* __restrict__ KVb, u16* __restrict__ Rh) {
  __shared__ __align__(16) u16 As[128 * 64];
  __shared__ __align__(16) u16 Bs[128 * 64];
  const int bid = blockIdx.x;
  const float* A; const u16* BT; u16* C; int ldc, bx, by;
  if (bid < 512)       { A = hidden; BT = WQT;  C = Qb;  ldc = 1024; bx = bid & 7;  by = bid >> 3; }
  else if (bid < 1536) { int r = bid - 512;  A = enc;    BT = WKVT; C = KVb; ldc = 2048; bx = r & 15; by = r >> 4; }
  else                 { int r = bid - 1536; A = relpos; BT = WRT;  C = Rh;  ldc = 1024; bx = r & 7;  by = r >> 3; }
  gemm_body_a32(A, BT, C, ldc, bx, by, As, Bs);
}

// ---------------- O-projection GEMM: C(f32) = A(bf16) @ BT^T
__global__ __launch_bounds__(256, 2) void gemm_o(
    const u16* __restrict__ Ap, const u16* __restrict__ BT, float* __restrict__ Cp) {
  __shared__ __align__(16) u16 As[128 * 64];
  __shared__ __align__(16) u16 Bs[128 * 64];
  const int t = threadIdx.x;
  const int lane = t & 63;
  const int w = t >> 6, wr = w >> 1, wc = w & 1;
  const int l15 = lane & 15, l4 = lane >> 4;
  const int row0 = blockIdx.y * 128, col0 = blockIdx.x * 128;
  f32x4 acc[4][4] = {};
  for (int k0 = 0; k0 < 1024; k0 += 64) {
#pragma unroll
    for (int q = 0; q < 4; q++) {
      int u = q * 256 + t;
      int r = u >> 3, c8 = u & 7;
      int sc8 = c8 ^ (r & 7);
      int ub = (q * 256 + (t & ~63)) * 8;
      gload16(BT + (size_t)(col0 + r) * 1024 + k0 + sc8 * 8, Bs + ub);
      gload16(Ap + (size_t)(row0 + r) * 1024 + k0 + sc8 * 8, As + ub);
    }
    __syncthreads();
#pragma unroll
    for (int kk = 0; kk < 2; kk++) {
      bf16x8 av[4], bv[4];
#pragma unroll
      for (int f = 0; f < 4; f++) {
        int kb = kk * 32 + l4 * 8;
        av[f] = rd8(As, wr * 64 + f * 16 + l15, kb);
        bv[f] = rd8(Bs, wc * 64 + f * 16 + l15, kb);
      }
#pragma unroll
      for (int fr = 0; fr < 4; fr++)
#pragma unroll
        for (int fc = 0; fc < 4; fc++)
          acc[fr][fc] = __builtin_amdgcn_mfma_f32_16x16x32_bf16(av[fr], bv[fc], acc[fr][fc], 0, 0, 0);
    }
    __syncthreads();
  }
#pragma unroll
  for (int fr = 0; fr < 4; fr++)
#pragma unroll
    for (int fc = 0; fc < 4; fc++) {
      int col = col0 + wc * 64 + fc * 16 + l15;
      int rw0 = row0 + wr * 64 + fr * 16 + l4 * 4;
#pragma unroll
      for (int r = 0; r < 4; r++)
        Cp[(size_t)(rw0 + r) * 1024 + col] = acc[fr][fc][r];
    }
}

// ---------------- corr[n][m] = (rrb - rwb)[n] . R[m]  (f32, 64KB)
__global__ void corr_kernel(const u16* __restrict__ Rh, const float* __restrict__ rwb,
                            const float* __restrict__ rrb, float* __restrict__ corrR) {
  const int m0 = blockIdx.x * 64, n = blockIdx.y;
  const int t = threadIdx.x, r = t >> 2, q = t & 3;
  float p = 0.f;
#pragma unroll
  for (int e = 0; e < 16; e++) {
    int d = q * 16 + e;
    p += (rrb[n * DHEAD + d] - rwb[n * DHEAD + d]) * bf2f(Rh[(size_t)(m0 + r) * DMODEL + n * DHEAD + d]);
  }
  p += __shfl_xor(p, 1, 4);
  p += __shfl_xor(p, 2, 4);
  if (q == 0) corrR[n * SEQ + m0 + r] = p;
}

// ---------------- fused flash attention + rolling on-the-fly BD (log2-domain softmax)
// [round-8 proven structure: Q staged to LDS; K/V/R via global_load_lds; wave-private D/P]
__global__ __launch_bounds__(256, 3) void flash_fused(
    const u16* __restrict__ Qb, const u16* __restrict__ KVb,
    const u16* __restrict__ VT, const u16* __restrict__ Rh,
    const float* __restrict__ rwb, const float* __restrict__ corrR,
    u16* __restrict__ AV) {
  __shared__ __align__(16) char smem[49408];
  u16* Qs = (u16*)smem;                 // 65 x 64 (Q + rwb)
  u16* Ks = (u16*)(smem + 8320);
  u16* Vs = (u16*)(smem + 16512);
  u16* Rs = (u16*)(smem + 24704);
  u16* Df = (u16*)(smem + 32896);       // 64 x 128 rolling D halves (+P overlay)
  const int t = threadIdx.x;
  const int lane = t & 63;
  const int w = t >> 6;
  const int l15 = lane & 15, l4 = lane >> 4;
  const int bid = blockIdx.x;
  const int sw = (bid & 7) * 256 + (bid >> 3);   // XCD swizzle
  const int i0 = (sw & 15) * 64;
  const int z = sw >> 4, b = z >> 4, n = z & 15;
  const float KSC = 0.18033688f;  // 0.125 * log2(e)

  // stage Qs = Q + rwb, rows i0..i0+64 (row 64 clamped)
#pragma unroll
  for (int p = 0; p < 3; p++) {
    int u = p * 256 + t;
    if (u < 520) {
      int r = u >> 3, c8 = u & 7;
      int sc8 = c8 ^ (r & 7);
      int rq = i0 + r; if (rq > SEQ - 1) rq = SEQ - 1;
      bf16x8 qv = *(const bf16x8*)(Qb + ((size_t)rq * BSZ + b) * DMODEL + n * DHEAD + sc8 * 8);
      f32x4 b0 = *(const f32x4*)(rwb + n * DHEAD + sc8 * 8);
      f32x4 b1 = *(const f32x4*)(rwb + n * DHEAD + sc8 * 8 + 4);
      union { unsigned u4[4]; bf16x8 v; } o;
      o.u4[0] = cvtpk(bf2f((u16)qv[0]) + b0[0], bf2f((u16)qv[1]) + b0[1]);
      o.u4[1] = cvtpk(bf2f((u16)qv[2]) + b0[2], bf2f((u16)qv[3]) + b0[3]);
      o.u4[2] = cvtpk(bf2f((u16)qv[4]) + b1[0], bf2f((u16)qv[5]) + b1[1]);
      o.u4[3] = cvtpk(bf2f((u16)qv[6]) + b1[2], bf2f((u16)qv[7]) + b1[3]);
      *(bf16x8*)(Qs + (size_t)u * 8) = o.v;
    }
  }
  // prologue D-tile: base = 960 - i0, qo = 0, half 0
  const int baseP = (SEQ - 64) - i0;
  const float* corrn = corrR + n * SEQ;
#pragma unroll
  for (int q = 0; q < 2; q++) {
    int u = q * 256 + t;
    int r = u >> 3, c8 = u & 7;
    int sc8 = c8 ^ (r & 7);
    int ub = (q * 256 + (t & ~63)) * 8;
    gload16(Rh + (size_t)(baseP + r) * DMODEL + n * DHEAD + sc8 * 8, Rs + ub);
  }
  float cP[4];
#pragma unroll
  for (int fc = 0; fc < 4; fc++) cP[fc] = corrn[baseP + fc * 16 + l15];
  __syncthreads();
  {
    f32x4 dp[4] = {};
#pragma unroll
    for (int kk = 0; kk < 2; kk++) {
      int kb = kk * 32 + l4 * 8;
      bf16x8 aQ = rd8(Qs, w * 16 + l15, kb);
#pragma unroll
      for (int fc = 0; fc < 4; fc++)
        dp[fc] = __builtin_amdgcn_mfma_f32_16x16x32_bf16(aQ, rd8(Rs, fc * 16 + l15, kb), dp[fc], 0, 0, 0);
    }
#pragma unroll
    for (int r = 0; r < 4; r++) {
      int row = w * 16 + l4 * 4 + r;
      unsigned d01 = cvtpk(dp[0][r] + cP[0], dp[1][r] + cP[1]);
      unsigned d23 = cvtpk(dp[2][r] + cP[2], dp[3][r] + cP[3]);
      wr128(Df, row, 0 * 16 + l15, (u16)d01);
      wr128(Df, row, 1 * 16 + l15, (u16)(d01 >> 16));
      wr128(Df, row, 2 * 16 + l15, (u16)d23);
      wr128(Df, row, 3 * 16 + l15, (u16)(d23 >> 16));
    }
  }
  f32x4 O[4] = {};
  float M[4], Lp[4];
#pragma unroll
  for (int r = 0; r < 4; r++) { M[r] = -1e30f; Lp[r] = 0.f; }
  float spec = 0.f;

  for (int jj = 0; jj < 16; jj++) {
    const int j0 = jj * 64;
    const int dlt = j0 - i0;
    const int base2 = (dlt < 0) ? dlt + SEQ : dlt;
    const int qo2 = (dlt >= 0) ? 1 : 0;
    const int off = (jj & 1) << 6;       // half holding the OLD tile (D1)
    __syncthreads();                      // all waves done reading Ks/Vs/Rs
#pragma unroll
    for (int q = 0; q < 2; q++) {
      int u = q * 256 + t;
      int r = u >> 3, c8 = u & 7;
      int sc8 = c8 ^ (r & 7);
      int ub = (q * 256 + (t & ~63)) * 8;
      gload16(KVb + ((size_t)(j0 + r) * BSZ + b) * (2 * DMODEL) + n * DHEAD + sc8 * 8, Ks + ub);
      gload16(VT + ((size_t)(b * NHEAD + n) * DHEAD + r) * SEQ + j0 + sc8 * 8, Vs + ub);
      gload16(Rh + (size_t)(base2 + r) * DMODEL + n * DHEAD + sc8 * 8, Rs + ub);
    }
    float cr[4];
#pragma unroll
    for (int fc = 0; fc < 4; fc++) cr[fc] = corrn[base2 + fc * 16 + l15];
    __syncthreads();
    // QK^T + new D-tile (8+8 MFMA)
    f32x4 sacc[4] = {}, dnew[4] = {};
    __builtin_amdgcn_s_setprio(1);
#pragma unroll
    for (int kk = 0; kk < 2; kk++) {
      int kb = kk * 32 + l4 * 8;
      int qr0 = w * 16 + l15;
      bf16x8 aQ = rd8(Qs, qr0, kb);
      bf16x8 aD = rd8(Qs, qr0 + qo2, kb);
#pragma unroll
      for (int fc = 0; fc < 4; fc++) {
        int br = fc * 16 + l15;
        sacc[fc] = __builtin_amdgcn_mfma_f32_16x16x32_bf16(aQ, rd8(Ks, br, kb), sacc[fc], 0, 0, 0);
        dnew[fc] = __builtin_amdgcn_mfma_f32_16x16x32_bf16(aD, rd8(Rs, br, kb), dnew[fc], 0, 0, 0);
      }
    }
    __builtin_amdgcn_s_setprio(0);
    // store new D (+corr) into the other half (own-wave strip)
    const int offn = off ^ 64;
#pragma unroll
    for (int r = 0; r < 4; r++) {
      int row = w * 16 + l4 * 4 + r;
      unsigned d01 = cvtpk(dnew[0][r] + cr[0], dnew[1][r] + cr[1]);
      unsigned d23 = cvtpk(dnew[2][r] + cr[2], dnew[3][r] + cr[3]);
      wr128(Df, row, offn + 0 * 16 + l15, (u16)d01);
      wr128(Df, row, offn + 1 * 16 + l15, (u16)(d01 >> 16));
      wr128(Df, row, offn + 2 * 16 + l15, (u16)d23);
      wr128(Df, row, offn + 3 * 16 + l15, (u16)(d23 >> 16));
    }
    // spec carry for next iter: old-half [63][63] (wave 3 strip; BEFORE P overwrites it)
    float specnext = 0.f;
    if (w == 3)
      specnext = bf2f(*(const u16*)((const char*)Df + ((63 * 256) | ((((off + 63) * 2) ^ 0x70)))));
    // gather BD (uniform dlt-specialized) + log2-softmax (defer-max 11.5) + P store
    const float fix = (dlt == 64) ? 0.f : spec;
#pragma unroll
    for (int r = 0; r < 4; r++) {
      const int lrow = w * 16 + l4 * 4 + r;
      const int rbase = lrow * 256;
      const int swz = (lrow & 7) << 4;
      float v2[4];
      if (dlt < 0) {
        const int K = off + 63 - lrow;
#pragma unroll
        for (int fc = 0; fc < 4; fc++) {
          int col = (fc * 16 + l15 + K) & 127;
          float bd = bf2f(*(const u16*)((const char*)Df + (rbase | ((col * 2) ^ swz))));
          v2[fc] = (sacc[fc][r] + bd) * KSC;
        }
      } else if (dlt == 0) {
#pragma unroll
        for (int fc = 0; fc < 4; fc++) {
          int dj = fc * 16 + l15 - lrow;
          int ul = (dj <= 0) ? dj + 63 : dj + 62;
          int col = (off + ul) & 127;
          float bd = bf2f(*(const u16*)((const char*)Df + (rbase | ((col * 2) ^ swz))));
          if (dj == 1) bd = 0.f;
          v2[fc] = (sacc[fc][r] + bd) * KSC;
        }
      } else {
        const int K = 62 - lrow;
#pragma unroll
        for (int fc = 0; fc < 4; fc++) {
          int ul = fc * 16 + l15 + K;
          int col = (off + ((ul < 0) ? 0 : ul)) & 127;
          float bd = bf2f(*(const u16*)((const char*)Df + (rbase | ((col * 2) ^ swz))));
          if (ul < 0) bd = fix;
          v2[fc] = (sacc[fc][r] + bd) * KSC;
        }
      }
      float tm = fmaxf(fmaxf(v2[0], v2[1]), fmaxf(v2[2], v2[3]));
      unsigned long long bal = __ballot(tm > M[r] + 11.5f);
      if ((bal >> (l4 * 16)) & 0xFFFFull) {
        for (int mk = 1; mk < 16; mk <<= 1) tm = fmaxf(tm, __shfl_xor(tm, mk, 16));
        float alpha = exp2v(M[r] - tm);
        Lp[r] *= alpha;
#pragma unroll
        for (int fd = 0; fd < 4; fd++) O[fd][r] *= alpha;
        M[r] = tm;
      }
      float e0 = exp2v(v2[0] - M[r]), e1 = exp2v(v2[1] - M[r]);
      float e2 = exp2v(v2[2] - M[r]), e3 = exp2v(v2[3] - M[r]);
      Lp[r] += (e0 + e1) + (e2 + e3);
      unsigned p01 = cvtpk(e0, e1), p23 = cvtpk(e2, e3);
      wr128(Df, lrow, off + 0 * 16 + l15, (u16)p01);
      wr128(Df, lrow, off + 1 * 16 + l15, (u16)(p01 >> 16));
      wr128(Df, lrow, off + 2 * 16 + l15, (u16)p23);
      wr128(Df, lrow, off + 3 * 16 + l15, (u16)(p23 >> 16));
    }
    spec = specnext;
    // PV
    __builtin_amdgcn_s_setprio(1);
#pragma unroll
    for (int kk = 0; kk < 2; kk++) {
      int kb = kk * 32 + l4 * 8;
      bf16x8 a = rd8_128(Df, w * 16 + l15, off + kb);
#pragma unroll
      for (int fd = 0; fd < 4; fd++)
        O[fd] = __builtin_amdgcn_mfma_f32_16x16x32_bf16(a, rd8(Vs, fd * 16 + l15, kb), O[fd], 0, 0, 0);
    }
    __builtin_amdgcn_s_setprio(0);
  }
  float Lf[4];
#pragma unroll
  for (int r = 0; r < 4; r++) {
    float Lt = Lp[r];
    for (int mk = 1; mk < 16; mk <<= 1) Lt += __shfl_xor(Lt, mk, 16);
    Lf[r] = 1.f / Lt;
  }
#pragma unroll
  for (int fd = 0; fd < 4; fd++) {
    int d = fd * 16 + l15;
    int iq0 = i0 + w * 16 + l4 * 4;
    unsigned p01 = cvtpk(O[fd][0] * Lf[0], O[fd][1] * Lf[1]);
    unsigned p23 = cvtpk(O[fd][2] * Lf[2], O[fd][3] * Lf[3]);
    AV[((size_t)(iq0 + 0) * BSZ + b) * DMODEL + n * DHEAD + d] = (u16)p01;
    AV[((size_t)(iq0 + 1) * BSZ + b) * DMODEL + n * DHEAD + d] = (u16)(p01 >> 16);
    AV[((size_t)(iq0 + 2) * BSZ + b) * DMODEL + n * DHEAD + d] = (u16)p23;
    AV[((size_t)(iq0 + 3) * BSZ + b) * DMODEL + n * DHEAD + d] = (u16)(p23 >> 16);
  }
}

// ---------------- all four weight transposes in one launch: out(CxR,bf16) = in(RxC,f32)^T
__global__ void wtrans4(const float* __restrict__ W_q, const float* __restrict__ W_kv,
                        const float* __restrict__ W_r, const float* __restrict__ W_o,
                        u16* __restrict__ WQT, u16* __restrict__ WKVT,
                        u16* __restrict__ WRT, u16* __restrict__ WOT) {
  __shared__ unsigned int lds[64][65];
  const int bid = blockIdx.x;
  const float* in; u16* out; int C, cx, cy;
  if (bid < 256)      { in = W_q;  out = WQT;  C = 1024; cx = bid & 15;        cy = bid >> 4; }
  else if (bid < 768) { in = W_kv; out = WKVT; C = 2048; cx = (bid - 256) & 31; cy = (bid - 256) >> 5; }
  else if (bid < 1024){ in = W_r;  out = WRT;  C = 1024; cx = (bid - 768) & 15; cy = (bid - 768) >> 4; }
  else                { in = W_o;  out = WOT;  C = 1024; cx = (bid - 1024) & 15; cy = (bid - 1024) >> 4; }
  const int R = 1024;
  const int t = threadIdx.x;
  const int c0 = cx * 64, r0 = cy * 64;
#pragma unroll
  for (int p = 0; p < 2; p++) {
    int u = p * 256 + t;
    int r = u >> 3, c8 = u & 7;
    const float* src = in + (size_t)(r0 + r) * C + c0 + c8 * 8;
    f32x4 v0 = *(const f32x4*)src;
    f32x4 v1 = *(const f32x4*)(src + 4);
    unsigned q0 = cvtpk(v0[0], v0[1]), q1 = cvtpk(v0[2], v0[3]);
    unsigned q2 = cvtpk(v1[0], v1[1]), q3 = cvtpk(v1[2], v1[3]);
    lds[r][c8 * 8 + 0] = (u16)q0; lds[r][c8 * 8 + 1] = (u16)(q0 >> 16);
    lds[r][c8 * 8 + 2] = (u16)q1; lds[r][c8 * 8 + 3] = (u16)(q1 >> 16);
    lds[r][c8 * 8 + 4] = (u16)q2; lds[r][c8 * 8 + 5] = (u16)(q2 >> 16);
    lds[r][c8 * 8 + 6] = (u16)q3; lds[r][c8 * 8 + 7] = (u16)(q3 >> 16);
  }
  __syncthreads();
#pragma unroll
  for (int p = 0; p < 2; p++) {
    int u = p * 256 + t;
    int r = u >> 3, c8 = u & 7;
    bf16x8 v;
#pragma unroll
    for (int e = 0; e < 8; e++) v[e] = (short)lds[c8 * 8 + e][r];
    *(bf16x8*)(out + (size_t)(c0 + r) * R + r0 + c8 * 8) = v;
  }
}

// ---------------- V^T builder (V = second half of KVb rows, stride 2048)
__global__ void vtrans(const u16* __restrict__ KVb, u16* __restrict__ VT) {
  __shared__ unsigned int lds[64][65];
  const int t = threadIdx.x;
  const int s0 = blockIdx.x * 64, n = blockIdx.y, b = blockIdx.z;
#pragma unroll
  for (int p = 0; p < 2; p++) {
    int u = p * 256 + t;
    int r = u >> 3, c8 = u & 7;
    const u16* src = KVb + ((size_t)(s0 + r) * BSZ + b) * (2 * DMODEL) + DMODEL + n * DHEAD + c8 * 8;
    bf16x8 v = *(const bf16x8*)src;
#pragma unroll
    for (int e = 0; e < 8; e++) lds[r][c8 * 8 + e] = (u16)v[e];
  }
  __syncthreads();
#pragma unroll
  for (int p = 0; p < 2; p++) {
    int u = p * 256 + t;
    int r = u >> 3, c8 = u & 7;
    bf16x8 v;
#pragma unroll
    for (int e = 0; e < 8; e++) v[e] = (short)lds[c8 * 8 + e][r];
    *(bf16x8*)(VT + ((size_t)(b * NHEAD + n) * DHEAD + r) * SEQ + s0 + c8 * 8) = v;
  }
}

// ---------------- residual + LayerNorm (f32, in-place on out)
__global__ void ln_kernel(const float* __restrict__ hidden,
                          const float* __restrict__ gamma, const float* __restrict__ beta,
                          float* __restrict__ out) {
  __shared__ float wsum[4];
  __shared__ float wvar[4];
  const int row = blockIdx.x;
  const int t = threadIdx.x;
  f32x4 hv = *(const f32x4*)(hidden + (size_t)row * DMODEL + t * 4);
  f32x4 ov = *(const f32x4*)(out + (size_t)row * DMODEL + t * 4);
  float xs[4], sum = 0.f;
#pragma unroll
  for (int e = 0; e < 4; e++) { xs[e] = hv[e] + ov[e]; sum += xs[e]; }
  for (int mk = 1; mk < 64; mk <<= 1) sum += __shfl_xor(sum, mk, 64);
  if ((t & 63) == 0) wsum[t >> 6] = sum;
  __syncthreads();
  float mu = (wsum[0] + wsum[1] + wsum[2] + wsum[3]) * (1.f / DMODEL);
  float var = 0.f;
#pragma unroll
  for (int e = 0; e < 4; e++) { float d = xs[e] - mu; var += d * d; }
  for (int mk = 1; mk < 64; mk <<= 1) var += __shfl_xor(var, mk, 64);
  if ((t & 63) == 0) wvar[t >> 6] = var;
  __syncthreads();
  float rstd = rsqrtf((wvar[0] + wvar[1] + wvar[2] + wvar[3]) * (1.f / DMODEL) + 1e-5f);
  f32x4 res;
#pragma unroll
  for (int e = 0; e < 4; e++) {
    int c = t * 4 + e;
    res[e] = (xs[e] - mu) * rstd * gamma[c] + beta[c];
  }
  *(f32x4*)(out + (size_t)row * DMODEL + t * 4) = res;
}

extern "C" void kernel_launch(void* const* d_in, const int* in_sizes, int n_in,
                              void* d_out, int out_size, void* d_ws, size_t ws_size,
                              hipStream_t stream) {
  const float* hidden = (const float*)d_in[0];
  const float* relpos = (const float*)d_in[1];
  const float* enc    = (const float*)d_in[2];
  const float* W_q    = (const float*)d_in[3];
  const float* W_kv   = (const float*)d_in[4];
  const float* W_r    = (const float*)d_in[5];
  const float* W_o    = (const float*)d_in[6];
  const float* rwb    = (const float*)d_in[7];
  const float* rrb    = (const float*)d_in[8];
  const float* gamma  = (const float*)d_in[9];
  const float* beta   = (const float*)d_in[10];
  float* out = (float*)d_out;

  char* ws = (char*)d_ws;
  size_t off = 0;
  auto alloc = [&](size_t bytes) { char* p = ws + off; off += (bytes + 255) & ~(size_t)255; return p; };
  const size_t MB = 1024 * 1024;
  u16* WOT  = (u16*)alloc(2 * MB);
  u16* Qb   = (u16*)alloc(16 * MB);
  u16* KVb  = (u16*)alloc(32 * MB);      // K cols 0..1023, V cols 1024..2047 per row
  u16* VT   = (u16*)alloc(16 * MB);
  u16* AV   = (u16*)alloc(16 * MB);
  u16* Rh   = (u16*)alloc(2 * MB);
  float* corrR = (float*)alloc(NHEAD * SEQ * 4);
  u16* WQT  = (u16*)alloc(2 * MB);
  u16* WKVT = (u16*)alloc(4 * MB);
  u16* WRT  = (u16*)alloc(2 * MB);
  (void)ws_size; (void)in_sizes; (void)n_in; (void)out_size;

  dim3 blk(256);
  wtrans4<<<dim3(1280), blk, 0, stream>>>(W_q, W_kv, W_r, W_o, WQT, WKVT, WRT, WOT);
  gemm3<<<dim3(1600), blk, 0, stream>>>(hidden, enc, relpos, WQT, WKVT, WRT, Qb, KVb, Rh);
  corr_kernel<<<dim3(16, NHEAD), blk, 0, stream>>>(Rh, rwb, rrb, corrR);
  vtrans<<<dim3(16, NHEAD, BSZ), blk, 0, stream>>>(KVb, VT);

  flash_fused<<<dim3(16 * BSZ * NHEAD), blk, 0, stream>>>(Qb, KVb, VT, Rh, rwb, corrR, AV);

  gemm_o<<<dim3(8, 64), blk, 0, stream>>>(AV, WOT, out);
  ln_kernel<<<dim3(8192), blk, 0, stream>>>(hidden, gamma, beta, out);
}

// Round 12
// 288.456 us; speedup vs baseline: 2.2474x; 1.0324x over previous
//
#include <hip/hip_runtime.h>
#include <stdint.h>

constexpr int SEQ = 1024;
constexpr int BSZ = 8;
constexpr int NHEAD = 16;
constexpr int DHEAD = 64;
constexpr int DMODEL = 1024;

using u16 = unsigned short;
using bf16x8 = __attribute__((ext_vector_type(8))) short;
using f32x4 = __attribute__((ext_vector_type(4))) float;

__device__ __forceinline__ float bf2f(u16 u) {
  union { unsigned int i; float f; } c; c.i = ((unsigned int)u) << 16; return c.f;
}
// HW packed f32->bf16 (RNE): lo16 = cvt(a), hi16 = cvt(b)
__device__ __forceinline__ unsigned cvtpk(float a, float b) {
  unsigned r; asm("v_cvt_pk_bf16_f32 %0, %1, %2" : "=v"(r) : "v"(a), "v"(b)); return r;
}
// HW 2^x
__device__ __forceinline__ float exp2v(float x) {
  float r; asm("v_exp_f32 %0, %1" : "=v"(r) : "v"(x)); return r;
}
// async global->LDS, 16B per lane; LDS dest = wave-uniform base + lane*16
__device__ __forceinline__ void gload16(const void* g, void* l) {
  __builtin_amdgcn_global_load_lds((const __attribute__((address_space(1))) void*)g,
                                   (__attribute__((address_space(3))) void*)l, 16, 0, 0);
}
__device__ __forceinline__ bf16x8 cvt8(const float* src) {
  f32x4 a = *(const f32x4*)src;
  f32x4 b = *(const f32x4*)(src + 4);
  union { unsigned u[4]; bf16x8 v; } o;
  o.u[0] = cvtpk(a[0], a[1]); o.u[1] = cvtpk(a[2], a[3]);
  o.u[2] = cvtpk(b[0], b[1]); o.u[3] = cvtpk(b[2], b[3]);
  return o.v;
}
// swizzled accessors: [*][64] tiles and the [64][128] D buffer
__device__ __forceinline__ bf16x8 rd8(const u16* base, int row, int col) {
  return *(const bf16x8*)((const char*)base + (((row * 64 + col) * 2) ^ ((row & 7) << 4)));
}
__device__ __forceinline__ bf16x8 rd8_128(const u16* base, int row, int col) {
  return *(const bf16x8*)((const char*)base + (((row * 128 + col) * 2) ^ ((row & 7) << 4)));
}
__device__ __forceinline__ void wr128(u16* base, int row, int col, u16 v) {
  *(u16*)((char*)base + (((row * 128 + col) * 2) ^ ((row & 7) << 4))) = v;
}

// ---------------- shared GEMM body: C(bf16) = A @ BT^T, 128x128, BK=64, K=1024
// a32: A is f32 (reg-staged cvt); else A is bf16 via global_load_lds.
__device__ __forceinline__ void gemm_body(
    const void* __restrict__ Ap, int a32, const u16* __restrict__ BT,
    u16* __restrict__ C, int ldc, int bx, int by, u16* As, u16* Bs) {
  const int t = threadIdx.x;
  const int lane = t & 63;
  const int w = t >> 6, wr = w >> 1, wc = w & 1;
  const int l15 = lane & 15, l4 = lane >> 4;
  const int row0 = by * 128, col0 = bx * 128;
  f32x4 acc[4][4] = {};
  for (int k0 = 0; k0 < 1024; k0 += 64) {
#pragma unroll
    for (int q = 0; q < 4; q++) {
      int u = q * 256 + t;
      int r = u >> 3, c8 = u & 7;
      int sc8 = c8 ^ (r & 7);
      int ub = (q * 256 + (t & ~63)) * 8;
      gload16(BT + (size_t)(col0 + r) * 1024 + k0 + sc8 * 8, Bs + ub);
      if (a32) {
        const float* src = (const float*)Ap + (size_t)(row0 + r) * 1024 + k0 + sc8 * 8;
        *(bf16x8*)(As + (size_t)u * 8) = cvt8(src);
      } else {
        gload16((const u16*)Ap + (size_t)(row0 + r) * 1024 + k0 + sc8 * 8, As + ub);
      }
    }
    __syncthreads();
#pragma unroll
    for (int kk = 0; kk < 2; kk++) {
      bf16x8 av[4], bv[4];
#pragma unroll
      for (int f = 0; f < 4; f++) {
        int kb = kk * 32 + l4 * 8;
        av[f] = rd8(As, wr * 64 + f * 16 + l15, kb);
        bv[f] = rd8(Bs, wc * 64 + f * 16 + l15, kb);
      }
#pragma unroll
      for (int fr = 0; fr < 4; fr++)
#pragma unroll
        for (int fc = 0; fc < 4; fc++)
          acc[fr][fc] = __builtin_amdgcn_mfma_f32_16x16x32_bf16(av[fr], bv[fc], acc[fr][fc], 0, 0, 0);
    }
    __syncthreads();
  }
#pragma unroll
  for (int fr = 0; fr < 4; fr++)
#pragma unroll
    for (int fc = 0; fc < 4; fc++) {
      int col = col0 + wc * 64 + fc * 16 + l15;
      int rw0 = row0 + wr * 64 + fr * 16 + l4 * 4;
      unsigned p01 = cvtpk(acc[fr][fc][0], acc[fr][fc][1]);
      unsigned p23 = cvtpk(acc[fr][fc][2], acc[fr][fc][3]);
      C[(size_t)(rw0 + 0) * ldc + col] = (u16)p01;
      C[(size_t)(rw0 + 1) * ldc + col] = (u16)(p01 >> 16);
      C[(size_t)(rw0 + 2) * ldc + col] = (u16)p23;
      C[(size_t)(rw0 + 3) * ldc + col] = (u16)(p23 >> 16);
    }
}

// ---------------- fused Q/KV/R projection launch (flat 1600-block grid)
// Q and KV read bf16 A (pre-converted); R reads f32 relpos.
__global__ __launch_bounds__(256, 2) void gemm3(
    const u16* __restrict__ hidden_bf, const u16* __restrict__ enc_bf,
    const float* __restrict__ relpos,
    const u16* __restrict__ WQT, const u16* __restrict__ WKVT, const u16* __restrict__ WRT,
    u16* __restrict__ Qb, u16* __restrict__ KVb, u16* __restrict__ Rh) {
  __shared__ __align__(16) u16 As[128 * 64];
  __shared__ __align__(16) u16 Bs[128 * 64];
  const int bid = blockIdx.x;
  const void* A; const u16* BT; u16* C; int ldc, bx, by, a32;
  if (bid < 512)       { A = hidden_bf; BT = WQT;  C = Qb;  ldc = 1024; bx = bid & 7;  by = bid >> 3; a32 = 0; }
  else if (bid < 1536) { int r = bid - 512;  A = enc_bf; BT = WKVT; C = KVb; ldc = 2048; bx = r & 15; by = r >> 4; a32 = 0; }
  else                 { int r = bid - 1536; A = relpos; BT = WRT;  C = Rh;  ldc = 1024; bx = r & 7;  by = r >> 3; a32 = 1; }
  gemm_body(A, a32, BT, C, ldc, bx, by, As, Bs);
}

// ---------------- O-projection GEMM: C(f32) = A(bf16) @ BT^T
__global__ __launch_bounds__(256, 2) void gemm_o(
    const u16* __restrict__ Ap, const u16* __restrict__ BT, float* __restrict__ Cp) {
  __shared__ __align__(16) u16 As[128 * 64];
  __shared__ __align__(16) u16 Bs[128 * 64];
  const int t = threadIdx.x;
  const int lane = t & 63;
  const int w = t >> 6, wr = w >> 1, wc = w & 1;
  const int l15 = lane & 15, l4 = lane >> 4;
  const int row0 = blockIdx.y * 128, col0 = blockIdx.x * 128;
  f32x4 acc[4][4] = {};
  for (int k0 = 0; k0 < 1024; k0 += 64) {
#pragma unroll
    for (int q = 0; q < 4; q++) {
      int u = q * 256 + t;
      int r = u >> 3, c8 = u & 7;
      int sc8 = c8 ^ (r & 7);
      int ub = (q * 256 + (t & ~63)) * 8;
      gload16(BT + (size_t)(col0 + r) * 1024 + k0 + sc8 * 8, Bs + ub);
      gload16(Ap + (size_t)(row0 + r) * 1024 + k0 + sc8 * 8, As + ub);
    }
    __syncthreads();
#pragma unroll
    for (int kk = 0; kk < 2; kk++) {
      bf16x8 av[4], bv[4];
#pragma unroll
      for (int f = 0; f < 4; f++) {
        int kb = kk * 32 + l4 * 8;
        av[f] = rd8(As, wr * 64 + f * 16 + l15, kb);
        bv[f] = rd8(Bs, wc * 64 + f * 16 + l15, kb);
      }
#pragma unroll
      for (int fr = 0; fr < 4; fr++)
#pragma unroll
        for (int fc = 0; fc < 4; fc++)
          acc[fr][fc] = __builtin_amdgcn_mfma_f32_16x16x32_bf16(av[fr], bv[fc], acc[fr][fc], 0, 0, 0);
    }
    __syncthreads();
  }
#pragma unroll
  for (int fr = 0; fr < 4; fr++)
#pragma unroll
    for (int fc = 0; fc < 4; fc++) {
      int col = col0 + wc * 64 + fc * 16 + l15;
      int rw0 = row0 + wr * 64 + fr * 16 + l4 * 4;
#pragma unroll
      for (int r = 0; r < 4; r++)
        Cp[(size_t)(rw0 + r) * 1024 + col] = acc[fr][fc][r];
    }
}

// ---------------- fused flash attention + rolling on-the-fly BD (log2-domain softmax)
// [round-8 proven structure, UNCHANGED]
__global__ __launch_bounds__(256, 3) void flash_fused(
    const u16* __restrict__ Qb, const u16* __restrict__ KVb,
    const u16* __restrict__ VT, const u16* __restrict__ Rh,
    const float* __restrict__ rwb, const float* __restrict__ corrR,
    u16* __restrict__ AV) {
  __shared__ __align__(16) char smem[49408];
  u16* Qs = (u16*)smem;                 // 65 x 64 (Q + rwb)
  u16* Ks = (u16*)(smem + 8320);
  u16* Vs = (u16*)(smem + 16512);
  u16* Rs = (u16*)(smem + 24704);
  u16* Df = (u16*)(smem + 32896);       // 64 x 128 rolling D halves (+P overlay)
  const int t = threadIdx.x;
  const int lane = t & 63;
  const int w = t >> 6;
  const int l15 = lane & 15, l4 = lane >> 4;
  const int bid = blockIdx.x;
  const int sw = (bid & 7) * 256 + (bid >> 3);   // XCD swizzle
  const int i0 = (sw & 15) * 64;
  const int z = sw >> 4, b = z >> 4, n = z & 15;
  const float KSC = 0.18033688f;  // 0.125 * log2(e)

  // stage Qs = Q + rwb, rows i0..i0+64 (row 64 clamped)
#pragma unroll
  for (int p = 0; p < 3; p++) {
    int u = p * 256 + t;
    if (u < 520) {
      int r = u >> 3, c8 = u & 7;
      int sc8 = c8 ^ (r & 7);
      int rq = i0 + r; if (rq > SEQ - 1) rq = SEQ - 1;
      bf16x8 qv = *(const bf16x8*)(Qb + ((size_t)rq * BSZ + b) * DMODEL + n * DHEAD + sc8 * 8);
      f32x4 b0 = *(const f32x4*)(rwb + n * DHEAD + sc8 * 8);
      f32x4 b1 = *(const f32x4*)(rwb + n * DHEAD + sc8 * 8 + 4);
      union { unsigned u4[4]; bf16x8 v; } o;
      o.u4[0] = cvtpk(bf2f((u16)qv[0]) + b0[0], bf2f((u16)qv[1]) + b0[1]);
      o.u4[1] = cvtpk(bf2f((u16)qv[2]) + b0[2], bf2f((u16)qv[3]) + b0[3]);
      o.u4[2] = cvtpk(bf2f((u16)qv[4]) + b1[0], bf2f((u16)qv[5]) + b1[1]);
      o.u4[3] = cvtpk(bf2f((u16)qv[6]) + b1[2], bf2f((u16)qv[7]) + b1[3]);
      *(bf16x8*)(Qs + (size_t)u * 8) = o.v;
    }
  }
  // prologue D-tile: base = 960 - i0, qo = 0, half 0
  const int baseP = (SEQ - 64) - i0;
  const float* corrn = corrR + n * SEQ;
#pragma unroll
  for (int q = 0; q < 2; q++) {
    int u = q * 256 + t;
    int r = u >> 3, c8 = u & 7;
    int sc8 = c8 ^ (r & 7);
    int ub = (q * 256 + (t & ~63)) * 8;
    gload16(Rh + (size_t)(baseP + r) * DMODEL + n * DHEAD + sc8 * 8, Rs + ub);
  }
  float cP[4];
#pragma unroll
  for (int fc = 0; fc < 4; fc++) cP[fc] = corrn[baseP + fc * 16 + l15];
  __syncthreads();
  {
    f32x4 dp[4] = {};
#pragma unroll
    for (int kk = 0; kk < 2; kk++) {
      int kb = kk * 32 + l4 * 8;
      bf16x8 aQ = rd8(Qs, w * 16 + l15, kb);
#pragma unroll
      for (int fc = 0; fc < 4; fc++)
        dp[fc] = __builtin_amdgcn_mfma_f32_16x16x32_bf16(aQ, rd8(Rs, fc * 16 + l15, kb), dp[fc], 0, 0, 0);
    }
#pragma unroll
    for (int r = 0; r < 4; r++) {
      int row = w * 16 + l4 * 4 + r;
      unsigned d01 = cvtpk(dp[0][r] + cP[0], dp[1][r] + cP[1]);
      unsigned d23 = cvtpk(dp[2][r] + cP[2], dp[3][r] + cP[3]);
      wr128(Df, row, 0 * 16 + l15, (u16)d01);
      wr128(Df, row, 1 * 16 + l15, (u16)(d01 >> 16));
      wr128(Df, row, 2 * 16 + l15, (u16)d23);
      wr128(Df, row, 3 * 16 + l15, (u16)(d23 >> 16));
    }
  }
  f32x4 O[4] = {};
  float M[4], Lp[4];
#pragma unroll
  for (int r = 0; r < 4; r++) { M[r] = -1e30f; Lp[r] = 0.f; }
  float spec = 0.f;

  for (int jj = 0; jj < 16; jj++) {
    const int j0 = jj * 64;
    const int dlt = j0 - i0;
    const int base2 = (dlt < 0) ? dlt + SEQ : dlt;
    const int qo2 = (dlt >= 0) ? 1 : 0;
    const int off = (jj & 1) << 6;       // half holding the OLD tile (D1)
    __syncthreads();                      // all waves done reading Ks/Vs/Rs
#pragma unroll
    for (int q = 0; q < 2; q++) {
      int u = q * 256 + t;
      int r = u >> 3, c8 = u & 7;
      int sc8 = c8 ^ (r & 7);
      int ub = (q * 256 + (t & ~63)) * 8;
      gload16(KVb + ((size_t)(j0 + r) * BSZ + b) * (2 * DMODEL) + n * DHEAD + sc8 * 8, Ks + ub);
      gload16(VT + ((size_t)(b * NHEAD + n) * DHEAD + r) * SEQ + j0 + sc8 * 8, Vs + ub);
      gload16(Rh + (size_t)(base2 + r) * DMODEL + n * DHEAD + sc8 * 8, Rs + ub);
    }
    float cr[4];
#pragma unroll
    for (int fc = 0; fc < 4; fc++) cr[fc] = corrn[base2 + fc * 16 + l15];
    __syncthreads();
    // QK^T + new D-tile (8+8 MFMA)
    f32x4 sacc[4] = {}, dnew[4] = {};
    __builtin_amdgcn_s_setprio(1);
#pragma unroll
    for (int kk = 0; kk < 2; kk++) {
      int kb = kk * 32 + l4 * 8;
      int qr0 = w * 16 + l15;
      bf16x8 aQ = rd8(Qs, qr0, kb);
      bf16x8 aD = rd8(Qs, qr0 + qo2, kb);
#pragma unroll
      for (int fc = 0; fc < 4; fc++) {
        int br = fc * 16 + l15;
        sacc[fc] = __builtin_amdgcn_mfma_f32_16x16x32_bf16(aQ, rd8(Ks, br, kb), sacc[fc], 0, 0, 0);
        dnew[fc] = __builtin_amdgcn_mfma_f32_16x16x32_bf16(aD, rd8(Rs, br, kb), dnew[fc], 0, 0, 0);
      }
    }
    __builtin_amdgcn_s_setprio(0);
    // store new D (+corr) into the other half (own-wave strip)
    const int offn = off ^ 64;
#pragma unroll
    for (int r = 0; r < 4; r++) {
      int row = w * 16 + l4 * 4 + r;
      unsigned d01 = cvtpk(dnew[0][r] + cr[0], dnew[1][r] + cr[1]);
      unsigned d23 = cvtpk(dnew[2][r] + cr[2], dnew[3][r] + cr[3]);
      wr128(Df, row, offn + 0 * 16 + l15, (u16)d01);
      wr128(Df, row, offn + 1 * 16 + l15, (u16)(d01 >> 16));
      wr128(Df, row, offn + 2 * 16 + l15, (u16)d23);
      wr128(Df, row, offn + 3 * 16 + l15, (u16)(d23 >> 16));
    }
    // spec carry for next iter: old-half [63][63] (wave 3 strip; BEFORE P overwrites it)
    float specnext = 0.f;
    if (w == 3)
      specnext = bf2f(*(const u16*)((const char*)Df + ((63 * 256) | ((((off + 63) * 2) ^ 0x70)))));
    // gather BD (uniform dlt-specialized) + log2-softmax (defer-max 11.5) + P store
    const float fix = (dlt == 64) ? 0.f : spec;
#pragma unroll
    for (int r = 0; r < 4; r++) {
      const int lrow = w * 16 + l4 * 4 + r;
      const int rbase = lrow * 256;
      const int swz = (lrow & 7) << 4;
      float v2[4];
      if (dlt < 0) {
        const int K = off + 63 - lrow;
#pragma unroll
        for (int fc = 0; fc < 4; fc++) {
          int col = (fc * 16 + l15 + K) & 127;
          float bd = bf2f(*(const u16*)((const char*)Df + (rbase | ((col * 2) ^ swz))));
          v2[fc] = (sacc[fc][r] + bd) * KSC;
        }
      } else if (dlt == 0) {
#pragma unroll
        for (int fc = 0; fc < 4; fc++) {
          int dj = fc * 16 + l15 - lrow;
          int ul = (dj <= 0) ? dj + 63 : dj + 62;
          int col = (off + ul) & 127;
          float bd = bf2f(*(const u16*)((const char*)Df + (rbase | ((col * 2) ^ swz))));
          if (dj == 1) bd = 0.f;
          v2[fc] = (sacc[fc][r] + bd) * KSC;
        }
      } else {
        const int K = 62 - lrow;
#pragma unroll
        for (int fc = 0; fc < 4; fc++) {
          int ul = fc * 16 + l15 + K;
          int col = (off + ((ul < 0) ? 0 : ul)) & 127;
          float bd = bf2f(*(const u16*)((const char*)Df + (rbase | ((col * 2) ^ swz))));
          if (ul < 0) bd = fix;
          v2[fc] = (sacc[fc][r] + bd) * KSC;
        }
      }
      float tm = fmaxf(fmaxf(v2[0], v2[1]), fmaxf(v2[2], v2[3]));
      unsigned long long bal = __ballot(tm > M[r] + 11.5f);
      if ((bal >> (l4 * 16)) & 0xFFFFull) {
        for (int mk = 1; mk < 16; mk <<= 1) tm = fmaxf(tm, __shfl_xor(tm, mk, 16));
        float alpha = exp2v(M[r] - tm);
        Lp[r] *= alpha;
#pragma unroll
        for (int fd = 0; fd < 4; fd++) O[fd][r] *= alpha;
        M[r] = tm;
      }
      float e0 = exp2v(v2[0] - M[r]), e1 = exp2v(v2[1] - M[r]);
      float e2 = exp2v(v2[2] - M[r]), e3 = exp2v(v2[3] - M[r]);
      Lp[r] += (e0 + e1) + (e2 + e3);
      unsigned p01 = cvtpk(e0, e1), p23 = cvtpk(e2, e3);
      wr128(Df, lrow, off + 0 * 16 + l15, (u16)p01);
      wr128(Df, lrow, off + 1 * 16 + l15, (u16)(p01 >> 16));
      wr128(Df, lrow, off + 2 * 16 + l15, (u16)p23);
      wr128(Df, lrow, off + 3 * 16 + l15, (u16)(p23 >> 16));
    }
    spec = specnext;
    // PV
    __builtin_amdgcn_s_setprio(1);
#pragma unroll
    for (int kk = 0; kk < 2; kk++) {
      int kb = kk * 32 + l4 * 8;
      bf16x8 a = rd8_128(Df, w * 16 + l15, off + kb);
#pragma unroll
      for (int fd = 0; fd < 4; fd++)
        O[fd] = __builtin_amdgcn_mfma_f32_16x16x32_bf16(a, rd8(Vs, fd * 16 + l15, kb), O[fd], 0, 0, 0);
    }
    __builtin_amdgcn_s_setprio(0);
  }
  float Lf[4];
#pragma unroll
  for (int r = 0; r < 4; r++) {
    float Lt = Lp[r];
    for (int mk = 1; mk < 16; mk <<= 1) Lt += __shfl_xor(Lt, mk, 16);
    Lf[r] = 1.f / Lt;
  }
#pragma unroll
  for (int fd = 0; fd < 4; fd++) {
    int d = fd * 16 + l15;
    int iq0 = i0 + w * 16 + l4 * 4;
    unsigned p01 = cvtpk(O[fd][0] * Lf[0], O[fd][1] * Lf[1]);
    unsigned p23 = cvtpk(O[fd][2] * Lf[2], O[fd][3] * Lf[3]);
    AV[((size_t)(iq0 + 0) * BSZ + b) * DMODEL + n * DHEAD + d] = (u16)p01;
    AV[((size_t)(iq0 + 1) * BSZ + b) * DMODEL + n * DHEAD + d] = (u16)(p01 >> 16);
    AV[((size_t)(iq0 + 2) * BSZ + b) * DMODEL + n * DHEAD + d] = (u16)p23;
    AV[((size_t)(iq0 + 3) * BSZ + b) * DMODEL + n * DHEAD + d] = (u16)(p23 >> 16);
  }
}

// ---------------- prep: 4 weight transposes + f32->bf16 convert of hidden/enc (one launch)
__global__ void prep(const float* __restrict__ W_q, const float* __restrict__ W_kv,
                     const float* __restrict__ W_r, const float* __restrict__ W_o,
                     u16* __restrict__ WQT, u16* __restrict__ WKVT,
                     u16* __restrict__ WRT, u16* __restrict__ WOT,
                     const float* __restrict__ hidden, const float* __restrict__ enc,
                     u16* __restrict__ hidden_bf, u16* __restrict__ enc_bf) {
  const int bid = blockIdx.x;
  const int t = threadIdx.x;
  if (bid >= 1280) {  // convert sections: 4096 blocks hidden, 4096 enc
    int r = bid - 1280;
    const float* src; u16* dst;
    if (r < 4096) { src = hidden; dst = hidden_bf; }
    else          { src = enc;    dst = enc_bf;    r -= 4096; }
    size_t idx = ((size_t)r * 256 + t) * 8;
    *(bf16x8*)(dst + idx) = cvt8(src + idx);
    return;
  }
  __shared__ unsigned int lds[64][65];
  const float* in; u16* out; int C, cx, cy;
  if (bid < 256)      { in = W_q;  out = WQT;  C = 1024; cx = bid & 15;         cy = bid >> 4; }
  else if (bid < 768) { in = W_kv; out = WKVT; C = 2048; cx = (bid - 256) & 31; cy = (bid - 256) >> 5; }
  else if (bid < 1024){ in = W_r;  out = WRT;  C = 1024; cx = (bid - 768) & 15; cy = (bid - 768) >> 4; }
  else                { in = W_o;  out = WOT;  C = 1024; cx = (bid - 1024) & 15; cy = (bid - 1024) >> 4; }
  const int R = 1024;
  const int c0 = cx * 64, r0 = cy * 64;
#pragma unroll
  for (int p = 0; p < 2; p++) {
    int u = p * 256 + t;
    int r = u >> 3, c8 = u & 7;
    const float* src = in + (size_t)(r0 + r) * C + c0 + c8 * 8;
    f32x4 v0 = *(const f32x4*)src;
    f32x4 v1 = *(const f32x4*)(src + 4);
    unsigned q0 = cvtpk(v0[0], v0[1]), q1 = cvtpk(v0[2], v0[3]);
    unsigned q2 = cvtpk(v1[0], v1[1]), q3 = cvtpk(v1[2], v1[3]);
    lds[r][c8 * 8 + 0] = (u16)q0; lds[r][c8 * 8 + 1] = (u16)(q0 >> 16);
    lds[r][c8 * 8 + 2] = (u16)q1; lds[r][c8 * 8 + 3] = (u16)(q1 >> 16);
    lds[r][c8 * 8 + 4] = (u16)q2; lds[r][c8 * 8 + 5] = (u16)(q2 >> 16);
    lds[r][c8 * 8 + 6] = (u16)q3; lds[r][c8 * 8 + 7] = (u16)(q3 >> 16);
  }
  __syncthreads();
#pragma unroll
  for (int p = 0; p < 2; p++) {
    int u = p * 256 + t;
    int r = u >> 3, c8 = u & 7;
    bf16x8 v;
#pragma unroll
    for (int e = 0; e < 8; e++) v[e] = (short)lds[c8 * 8 + e][r];
    *(bf16x8*)(out + (size_t)(c0 + r) * R + r0 + c8 * 8) = v;
  }
}

// ---------------- V^T builder + corr table (one launch; flat grid 2304)
__global__ void vtrans_corr(const u16* __restrict__ KVb, u16* __restrict__ VT,
                            const u16* __restrict__ Rh, const float* __restrict__ rwb,
                            const float* __restrict__ rrb, float* __restrict__ corrR) {
  const int bid = blockIdx.x;
  const int t = threadIdx.x;
  if (bid >= 2048) {  // corr section
    int rr = bid - 2048;
    const int m0 = (rr & 15) * 64, n = rr >> 4;
    const int r = t >> 2, q = t & 3;
    float p = 0.f;
#pragma unroll
    for (int e = 0; e < 16; e++) {
      int d = q * 16 + e;
      p += (rrb[n * DHEAD + d] - rwb[n * DHEAD + d]) * bf2f(Rh[(size_t)(m0 + r) * DMODEL + n * DHEAD + d]);
    }
    p += __shfl_xor(p, 1, 4);
    p += __shfl_xor(p, 2, 4);
    if (q == 0) corrR[n * SEQ + m0 + r] = p;
    return;
  }
  __shared__ unsigned int lds[64][65];
  const int s0 = (bid & 15) * 64, n = (bid >> 4) & 15, b = bid >> 8;
#pragma unroll
  for (int p = 0; p < 2; p++) {
    int u = p * 256 + t;
    int r = u >> 3, c8 = u & 7;
    const u16* src = KVb + ((size_t)(s0 + r) * BSZ + b) * (2 * DMODEL) + DMODEL + n * DHEAD + c8 * 8;
    bf16x8 v = *(const bf16x8*)src;
#pragma unroll
    for (int e = 0; e < 8; e++) lds[r][c8 * 8 + e] = (u16)v[e];
  }
  __syncthreads();
#pragma unroll
  for (int p = 0; p < 2; p++) {
    int u = p * 256 + t;
    int r = u >> 3, c8 = u & 7;
    bf16x8 v;
#pragma unroll
    for (int e = 0; e < 8; e++) v[e] = (short)lds[c8 * 8 + e][r];
    *(bf16x8*)(VT + ((size_t)(b * NHEAD + n) * DHEAD + r) * SEQ + s0 + c8 * 8) = v;
  }
}

// ---------------- residual + LayerNorm (f32, in-place on out)
__global__ void ln_kernel(const float* __restrict__ hidden,
                          const float* __restrict__ gamma, const float* __restrict__ beta,
                          float* __restrict__ out) {
  __shared__ float wsum[4];
  __shared__ float wvar[4];
  const int row = blockIdx.x;
  const int t = threadIdx.x;
  f32x4 hv = *(const f32x4*)(hidden + (size_t)row * DMODEL + t * 4);
  f32x4 ov = *(const f32x4*)(out + (size_t)row * DMODEL + t * 4);
  float xs[4], sum = 0.f;
#pragma unroll
  for (int e = 0; e < 4; e++) { xs[e] = hv[e] + ov[e]; sum += xs[e]; }
  for (int mk = 1; mk < 64; mk <<= 1) sum += __shfl_xor(sum, mk, 64);
  if ((t & 63) == 0) wsum[t >> 6] = sum;
  __syncthreads();
  float mu = (wsum[0] + wsum[1] + wsum[2] + wsum[3]) * (1.f / DMODEL);
  float var = 0.f;
#pragma unroll
  for (int e = 0; e < 4; e++) { float d = xs[e] - mu; var += d * d; }
  for (int mk = 1; mk < 64; mk <<= 1) var += __shfl_xor(var, mk, 64);
  if ((t & 63) == 0) wvar[t >> 6] = var;
  __syncthreads();
  float rstd = rsqrtf((wvar[0] + wvar[1] + wvar[2] + wvar[3]) * (1.f / DMODEL) + 1e-5f);
  f32x4 res;
#pragma unroll
  for (int e = 0; e < 4; e++) {
    int c = t * 4 + e;
    res[e] = (xs[e] - mu) * rstd * gamma[c] + beta[c];
  }
  *(f32x4*)(out + (size_t)row * DMODEL + t * 4) = res;
}

extern "C" void kernel_launch(void* const* d_in, const int* in_sizes, int n_in,
                              void* d_out, int out_size, void* d_ws, size_t ws_size,
                              hipStream_t stream) {
  const float* hidden = (const float*)d_in[0];
  const float* relpos = (const float*)d_in[1];
  const float* enc    = (const float*)d_in[2];
  const float* W_q    = (const float*)d_in[3];
  const float* W_kv   = (const float*)d_in[4];
  const float* W_r    = (const float*)d_in[5];
  const float* W_o    = (const float*)d_in[6];
  const float* rwb    = (const float*)d_in[7];
  const float* rrb    = (const float*)d_in[8];
  const float* gamma  = (const float*)d_in[9];
  const float* beta   = (const float*)d_in[10];
  float* out = (float*)d_out;

  char* ws = (char*)d_ws;
  size_t off = 0;
  auto alloc = [&](size_t bytes) { char* p = ws + off; off += (bytes + 255) & ~(size_t)255; return p; };
  const size_t MB = 1024 * 1024;
  u16* WOT  = (u16*)alloc(2 * MB);
  u16* Qb   = (u16*)alloc(16 * MB);
  u16* KVb  = (u16*)alloc(32 * MB);      // K cols 0..1023, V cols 1024..2047 per row
  u16* VT   = (u16*)alloc(16 * MB);      // ALSO enc_bf (dead after gemm3)
  u16* AV   = (u16*)alloc(16 * MB);      // ALSO hidden_bf (dead after gemm3)
  u16* Rh   = (u16*)alloc(2 * MB);
  float* corrR = (float*)alloc(NHEAD * SEQ * 4);
  u16* WQT  = (u16*)alloc(2 * MB);
  u16* WKVT = (u16*)alloc(4 * MB);
  u16* WRT  = (u16*)alloc(2 * MB);
  u16* hidden_bf = AV;
  u16* enc_bf    = VT;
  (void)ws_size; (void)in_sizes; (void)n_in; (void)out_size;

  dim3 blk(256);
  prep<<<dim3(9472), blk, 0, stream>>>(W_q, W_kv, W_r, W_o, WQT, WKVT, WRT, WOT,
                                       hidden, enc, hidden_bf, enc_bf);
  gemm3<<<dim3(1600), blk, 0, stream>>>(hidden_bf, enc_bf, relpos, WQT, WKVT, WRT, Qb, KVb, Rh);
  vtrans_corr<<<dim3(2304), blk, 0, stream>>>(KVb, VT, Rh, rwb, rrb, corrR);

  flash_fused<<<dim3(16 * BSZ * NHEAD), blk, 0, stream>>>(Qb, KVb, VT, Rh, rwb, corrR, AV);

  gemm_o<<<dim3(8, 64), blk, 0, stream>>>(AV, WOT, out);
  ln_kernel<<<dim3(8192), blk, 0, stream>>>(hidden, gamma, beta, out);
}